// Round 1
// 24779.181 us; speedup vs baseline: 1.7932x; 1.7932x over previous
//
#include <hip/hip_runtime.h>

typedef unsigned short u16;
typedef short s8v __attribute__((ext_vector_type(8)));
typedef float f4v __attribute__((ext_vector_type(4)));

#define MFMA16 __builtin_amdgcn_mfma_f32_16x16x32_bf16

// ---------- scalar helpers ----------
__device__ __forceinline__ float bf2f(u16 u) {
  union { unsigned int i; float f; } c; c.i = ((unsigned int)u) << 16; return c.f;
}
__device__ __forceinline__ u16 f2bf(float f) {
  union { float f; unsigned int i; } c; c.f = f;
  unsigned int i = c.i;
  unsigned int r = i + 0x7FFFu + ((i >> 16) & 1u);  // RNE
  return (u16)(r >> 16);
}
__device__ __forceinline__ float sigm(float x) {
  float e = __builtin_amdgcn_exp2f(-1.44269504f * x);
  return __builtin_amdgcn_rcpf(1.0f + e);
}
__device__ __forceinline__ float tanh_(float x) {
  float e = __builtin_amdgcn_exp2f(2.88539009f * x);   // e^(2x)
  return 1.0f - 2.0f * __builtin_amdgcn_rcpf(e + 1.0f);
}
__device__ __forceinline__ void store_out(void* out, int mode, long idx, float v) {
  if (mode) ((float*)out)[idx] = v;
  else      ((u16*)out)[idx] = f2bf(v);
}

// ---------- dtype detector ----------
__global__ void k_detect(const u16* __restrict__ raw, int* __restrict__ flag) {
  __shared__ int cnt[256];
  int c = 0;
  for (int j = 0; j < 8; ++j) {
    int i = (threadIdx.x * 8 + j) * 2;
    int e = (raw[i] >> 7) & 0xFF;
    c += (e >= 130);
  }
  cnt[threadIdx.x] = c;
  __syncthreads();
  if (threadIdx.x == 0) {
    int s = 0;
    for (int i = 0; i < 256; ++i) s += cnt[i];
    *flag = (s > 64) ? 1 : 0;
  }
}

// ---------- normalize input to bf16 ----------
__global__ void k_conv(const void* __restrict__ src, u16* __restrict__ dst,
                       int n, const int* __restrict__ flag) {
  int mode = *flag;
  int i = blockIdx.x * blockDim.x + threadIdx.x;
  int st = gridDim.x * blockDim.x;
  if (mode) {
    const float* s = (const float*)src;
    for (; i < n; i += st) dst[i] = f2bf(s[i]);
  } else {
    const u16* s = (const u16*)src;
    for (; i < n; i += st) dst[i] = s[i];
  }
}

// ---------- zero init ----------
__global__ void k_zero(unsigned int* p, int n) {
  int i = blockIdx.x * blockDim.x + threadIdx.x;
  int st = gridDim.x * blockDim.x;
  for (; i < n; i += st) p[i] = 0u;
}

// ---------- device-wide barrier (2-level, cumulative counters, no reset) ----------
// bar[0]=epoch, bar[64]=root, bar[128+64*i]=leaf i (16 leaves, 16 blocks each)
__device__ __forceinline__ void gsync(unsigned* bar, unsigned* sep) {
  __syncthreads();
  if (threadIdx.x == 0) {
    unsigned e = *sep;
    __threadfence();                                    // release prior writes
    unsigned* leaf = bar + 128 + ((blockIdx.x & 15) << 6);
    if (atomicAdd(leaf, 1u) == e * 16u + 15u) {
      if (atomicAdd(bar + 64, 1u) == e * 16u + 15u)
        __hip_atomic_fetch_add(bar, 1u, __ATOMIC_RELEASE, __HIP_MEMORY_SCOPE_AGENT);
    }
    while (__hip_atomic_load(bar, __ATOMIC_RELAXED, __HIP_MEMORY_SCOPE_AGENT) <= e)
      __builtin_amdgcn_s_sleep(1);
    *sep = e + 1;
    __threadfence();                                    // acquire
  }
  __syncthreads();
}

// ---------- persistent-kernel shared state (145 KB of 160 KB) ----------
struct __align__(16) SMem {
  u16 W[26112];      // 52224B: dec gate-weight slice, fragment-major (enc overlay at front)
  u16 proj[25600];   // 51200B: this block's 25-row proj slice (persistent all 400 steps)
  u16 wsd[16384];    // 32768B: Ws_dec / Wout column-tile (blocks 0-68), Wstop (block 69)
  u16 v[1024];       //  2048B
  float hp[1024];    //  4096B: hp[bA,:] staged per attention phase
  float exl[32];     //   128B: exp(energy) for this block's 25 positions
  float gsc[512];    //  2048B: MFMA->cell regroup scratch
  float cst[128];    //   512B: LSTM c-state (enc: 64, dec: 128)
  unsigned ep;       // barrier epoch
};

struct P {
  const int* text;
  const u16 *emb, *eWihF, *eWhhF, *ebF, *eWihB, *eWhhB, *ebB;
  const u16 *Ws, *bs, *vv, *dWih, *dWhh, *db, *Wout, *bout, *Wstop, *bstop, *mel;
  u16 *enc_out, *proj;
  float *hp, *ctx, *sumexp;
  u16 *h_f, *h_b, *h_dec;
  void* out;
  const int* flag;
  unsigned* bar;
};

__global__ void __launch_bounds__(256, 1) k_all(P p) {
  __shared__ SMem sm;
  const int tid = threadIdx.x;
  const int bk = blockIdx.x;
  const int lane = tid & 63;
  const int wv = tid >> 6;
  const int q = lane >> 4, l15 = lane & 15;
  const s8v zero8 = {0, 0, 0, 0, 0, 0, 0, 0};
  if (tid == 0) sm.ep = 0;
  const int mode = *p.flag;

  // ================= encoder: block = (dir, mtile, 4-col group) =================
  const int dirE = bk >> 7;
  const int mtE = (bk >> 6) & 1;
  const int j0E = (bk & 63) * 4;
  {
    const u16* Wih = dirE ? p.eWihB : p.eWihF;
    const u16* Whh = dirE ? p.eWhhB : p.eWhhF;
    for (int i = tid; i < 1024; i += 256) {            // 64 frags x 16 rows
      int f = i >> 4, nl = i & 15;
      int row = (nl >> 2) * 256 + j0E + (nl & 3);      // gate*256 + col
      int k = f * 8;
      const u16* src = (k < 256) ? (Wih + row * 256 + k) : (Whh + row * 256 + k - 256);
      *(s8v*)(sm.W + (size_t)i * 8) = *(const s8v*)src;
    }
    if (tid < 64) sm.cst[tid] = 0.f;
  }
  float ebias;
  {
    const u16* eb = dirE ? p.ebB : p.ebF;
    ebias = bf2f(eb[(l15 >> 2) * 256 + j0E + (l15 & 3)]);
  }
  __syncthreads();
  {
    u16* hbuf = dirE ? p.h_b : p.h_f;
    for (int stp = 0; stp < 200; ++stp) {
      int tb = dirE ? (199 - stp) : stp;
      const u16* hR = hbuf + (stp & 1) * 8192;
      u16* hW = hbuf + ((stp + 1) & 1) * 8192;
      if (wv == 0) {
        int m = mtE * 16 + l15;
        const u16* xrow = p.emb + (long)p.text[m * 200 + tb] * 256;
        const u16* hrow = hR + m * 256;
        f4v acc = {ebias, ebias, ebias, ebias};
#pragma unroll
        for (int kc = 0; kc < 16; ++kc) {
          int k8 = kc * 32 + q * 8;
          s8v a = (k8 < 256) ? *(const s8v*)(xrow + k8) : *(const s8v*)(hrow + k8 - 256);
          s8v b = *(const s8v*)(sm.W + (size_t)((kc * 4 + q) * 16 + l15) * 8);
          acc = MFMA16(a, b, acc, 0, 0, 0);
        }
#pragma unroll
        for (int r = 0; r < 4; ++r) sm.gsc[(q * 4 + r) * 16 + l15] = acc[r];
      }
      __syncthreads();
      if (tid < 64) {
        int bl = tid >> 2, jj = tid & 3;
        float iG = sm.gsc[bl * 16 + jj];
        float fG = sm.gsc[bl * 16 + 4 + jj];
        float gG = sm.gsc[bl * 16 + 8 + jj];
        float oG = sm.gsc[bl * 16 + 12 + jj];
        float cold = sm.cst[tid];
        float cn = sigm(fG) * cold + sigm(iG) * tanh_(gG);
        float hn = sigm(oG) * tanh_(cn);
        sm.cst[tid] = cn;
        u16 hb16 = f2bf(hn);
        int b = mtE * 16 + bl;
        int col = j0E + jj;
        hW[b * 256 + col] = hb16;
        p.enc_out[((long)b * 200 + tb) * 512 + dirE * 256 + col] = hb16;
      }
      gsync(p.bar, &sm.ep);
    }
  }

  // ================= proj = enc_out @ Ws_enc^T + bs =================
  {
    int w = bk * 4 + wv;
    for (int j = 0; j < 25; ++j) {
      int job = w * 25 + j;
      int mt = job >> 6, nt = job & 63;
      int m = mt * 16 + l15;
      const u16* arow = p.enc_out + (long)m * 512;
      int n = nt * 16 + l15;
      const u16* brow = p.Ws + (long)n * 1536;
      f4v acc = {0.f, 0.f, 0.f, 0.f};
#pragma unroll
      for (int kc = 0; kc < 16; ++kc) {
        s8v a = *(const s8v*)(arow + kc * 32 + q * 8);
        s8v b = *(const s8v*)(brow + kc * 32 + q * 8);
        acc = MFMA16(a, b, acc, 0, 0, 0);
      }
      float bias = bf2f(p.bs[n]);
#pragma unroll
      for (int r = 0; r < 4; ++r)
        p.proj[(long)(mt * 16 + q * 4 + r) * 1024 + n] = f2bf(acc[r] + bias);
    }
  }
  gsync(p.bar, &sm.ep);

  // ================= decoder staging (all LDS-local) =================
  const int bA = bk >> 3, s0A = (bk & 7) * 25;         // attention identity
  float dbias, obias = 0.f;
  {
    int j0 = bk * 4;                                    // this block's 4 h-columns
    for (int i = tid; i < 3264; i += 256) {             // 204 frags x 16 rows
      int f = i >> 4, nl = i & 15;
      long row = (long)(nl >> 2) * 1024 + j0 + (nl & 3);
      int k = f * 8;
      s8v val;
      if (k < 592)       val = *(const s8v*)(p.dWih + row * 592 + k);
      else if (k < 1616) val = *(const s8v*)(p.dWhh + row * 1024 + k - 592);
      else               val = zero8;
      *(s8v*)(sm.W + (size_t)i * 8) = val;
    }
    dbias = bf2f(p.db[(l15 >> 2) * 1024 + j0 + (l15 & 3)]);
    if (bk < 69) {
      const u16* base = (bk < 64) ? (p.Ws + 512) : p.Wout;
      long rstr = (bk < 64) ? 1536 : 1024;
      long r0 = (bk < 64) ? bk * 16 : (long)(bk - 64) * 16;
      for (int i = tid; i < 2048; i += 256) {           // 128 frags x 16 rows
        int f = i >> 4, nl = i & 15;
        *(s8v*)(sm.wsd + (size_t)i * 8) = *(const s8v*)(base + (r0 + nl) * rstr + f * 8);
      }
      if (bk >= 64) obias = bf2f(p.bout[(bk - 64) * 16 + l15]);
    } else if (bk == 69) {
      if (tid < 128) *(s8v*)(sm.wsd + tid * 8) = *(const s8v*)(p.Wstop + tid * 8);
    }
    const u16* psrc = p.proj + (long)(bA * 200 + s0A) * 1024;
    for (int i = tid * 8; i < 25600; i += 2048)
      *(s8v*)(sm.proj + i) = *(const s8v*)(psrc + i);
    if (tid < 128) *(s8v*)(sm.v + tid * 8) = *(const s8v*)(p.vv + tid * 8);
    if (tid < 128) sm.cst[tid] = 0.f;
  }
  __syncthreads();

  // ================= decoder loop: 3 barriers/step =================
  for (int t = 0; t <= 400; ++t) {
    const u16* hR = p.h_dec + (t & 1) * 32768;
    u16* hW = p.h_dec + ((t + 1) & 1) * 32768;
    // ---- phase H: hp / mel(t-1) / stop(t-1) / zero ctx+sumexp ----
    if (bk < 64) {
      if (t < 400 && wv < 2) {
        int m = wv * 16 + l15;
        const u16* arow = hR + m * 1024;
        f4v acc = {0.f, 0.f, 0.f, 0.f};
#pragma unroll 8
        for (int kc = 0; kc < 32; ++kc) {
          s8v a = *(const s8v*)(arow + kc * 32 + q * 8);
          s8v b = *(const s8v*)(sm.wsd + (size_t)((kc * 4 + q) * 16 + l15) * 8);
          acc = MFMA16(a, b, acc, 0, 0, 0);
        }
        int n = bk * 16 + l15;
#pragma unroll
        for (int r = 0; r < 4; ++r)
          p.hp[(wv * 16 + q * 4 + r) * 1024 + n] = acc[r];
      }
    } else if (bk < 69) {
      if (t > 0 && wv < 2) {
        int m = wv * 16 + l15;
        const u16* arow = hR + m * 1024;
        f4v acc = {0.f, 0.f, 0.f, 0.f};
#pragma unroll 8
        for (int kc = 0; kc < 32; ++kc) {
          s8v a = *(const s8v*)(arow + kc * 32 + q * 8);
          s8v b = *(const s8v*)(sm.wsd + (size_t)((kc * 4 + q) * 16 + l15) * 8);
          acc = MFMA16(a, b, acc, 0, 0, 0);
        }
        int n = (bk - 64) * 16 + l15;
#pragma unroll
        for (int r = 0; r < 4; ++r)
          store_out(p.out, mode, ((long)(wv * 16 + q * 4 + r) * 400 + (t - 1)) * 80 + n,
                    acc[r] + obias);
      }
    } else if (bk == 69) {
      if (t > 0) {
        int b = tid >> 3, kp = tid & 7;
        const u16* hrow = hR + b * 1024;
        float s = 0.f;
        for (int k = kp * 128; k < kp * 128 + 128; ++k)
          s += bf2f(hrow[k]) * bf2f(sm.wsd[k]);
        s += __shfl_xor(s, 1, 64);
        s += __shfl_xor(s, 2, 64);
        s += __shfl_xor(s, 4, 64);
        if (kp == 0)
          store_out(p.out, mode, 1024000 + (long)b * 400 + (t - 1),
                    sigm(s + bf2f(p.bstop[0])));
      }
    } else if (bk < 134) {
      p.ctx[(bk - 70) * 256 + tid] = 0.f;
    } else if (bk == 134) {
      if (tid < 32) p.sumexp[tid] = 0.f;
    }
    if (t == 400) break;
    gsync(p.bar, &sm.ep);

    // ---- phase A: attention for (bA, 25 positions) ----
    for (int i = tid; i < 1024; i += 256) sm.hp[i] = p.hp[bA * 1024 + i];
    __syncthreads();
    {
      f4v h0a = *(const f4v*)(sm.hp + lane * 8);
      f4v h0b = *(const f4v*)(sm.hp + lane * 8 + 4);
      f4v h1a = *(const f4v*)(sm.hp + 512 + lane * 8);
      f4v h1b = *(const f4v*)(sm.hp + 512 + lane * 8 + 4);
      s8v v0 = *(const s8v*)(sm.v + lane * 8);
      s8v v1 = *(const s8v*)(sm.v + 512 + lane * 8);
      for (int si = wv; si < 25; si += 4) {
        const u16* prow = sm.proj + si * 1024;
        s8v p0 = *(const s8v*)(prow + lane * 8);
        s8v p1 = *(const s8v*)(prow + 512 + lane * 8);
        float part = 0.f;
#pragma unroll
        for (int jj = 0; jj < 4; ++jj) {
          part += tanh_(bf2f((u16)p0[jj]) + h0a[jj]) * bf2f((u16)v0[jj]);
          part += tanh_(bf2f((u16)p0[jj + 4]) + h0b[jj]) * bf2f((u16)v0[jj + 4]);
          part += tanh_(bf2f((u16)p1[jj]) + h1a[jj]) * bf2f((u16)v1[jj]);
          part += tanh_(bf2f((u16)p1[jj + 4]) + h1b[jj]) * bf2f((u16)v1[jj + 4]);
        }
#pragma unroll
        for (int off = 32; off >= 1; off >>= 1) part += __shfl_xor(part, off, 64);
        if (lane == 0) sm.exl[si] = __builtin_amdgcn_exp2f(1.44269504f * part);
      }
    }
    __syncthreads();
    if (tid == 0) {
      float ss = 0.f;
      for (int i = 0; i < 25; ++i) ss += sm.exl[i];
      atomicAdd(&p.sumexp[bA], ss);
    }
    {
      int e0 = tid * 2;
      float a0 = 0.f, a1 = 0.f;
      const u16* eb = p.enc_out + (long)(bA * 200 + s0A) * 512 + e0;
#pragma unroll 5
      for (int i = 0; i < 25; ++i) {
        float w = sm.exl[i];
        unsigned pr = *(const unsigned*)(eb + (size_t)i * 512);
        a0 += w * bf2f((u16)(pr & 0xffffu));
        a1 += w * bf2f((u16)(pr >> 16));
      }
      atomicAdd(&p.ctx[bA * 512 + e0], a0);
      atomicAdd(&p.ctx[bA * 512 + e0 + 1], a1);
    }
    gsync(p.bar, &sm.ep);

    // ---- phase G: gates GEMM (K=1616) + LSTM cell + aligns ----
    if (wv == 2 && lane < 25) {
      float rs = __builtin_amdgcn_rcpf(p.sumexp[bA]);
      store_out(p.out, mode, 1036800 + ((long)bA * 400 + t) * 200 + s0A + lane,
                sm.exl[lane] * rs);
    }
    if (wv < 2) {
      int m = wv * 16 + l15;
      float rsm = __builtin_amdgcn_rcpf(p.sumexp[m]);
      const u16* melrow = p.mel + ((long)m * 400 + (t - 1)) * 80;
      const u16* hrow = hR + m * 1024;
      const float* crow = p.ctx + m * 512;
      f4v acc = {dbias, dbias, dbias, dbias};
      for (int kc = 0; kc < 51; ++kc) {
        int k8 = kc * 32 + q * 8;
        s8v a;
        if (k8 < 80) {
          a = (t == 0) ? zero8 : *(const s8v*)(melrow + k8);
        } else if (k8 < 592) {
          f4v c0 = *(const f4v*)(crow + k8 - 80);
          f4v c1 = *(const f4v*)(crow + k8 - 76);
          s8v t8;
#pragma unroll
          for (int jj = 0; jj < 4; ++jj) {
            t8[jj] = (short)f2bf(c0[jj] * rsm);
            t8[jj + 4] = (short)f2bf(c1[jj] * rsm);
          }
          a = t8;
        } else if (k8 < 1616) {
          a = *(const s8v*)(hrow + k8 - 592);
        } else {
          a = zero8;
        }
        s8v b = *(const s8v*)(sm.W + (size_t)((kc * 4 + q) * 16 + l15) * 8);
        acc = MFMA16(a, b, acc, 0, 0, 0);
      }
#pragma unroll
      for (int r = 0; r < 4; ++r) sm.gsc[(wv * 16 + q * 4 + r) * 16 + l15] = acc[r];
    }
    __syncthreads();
    if (tid < 128) {
      int bl = tid >> 2, jj = tid & 3;
      float iG = sm.gsc[bl * 16 + jj];
      float fG = sm.gsc[bl * 16 + 4 + jj];
      float gG = sm.gsc[bl * 16 + 8 + jj];
      float oG = sm.gsc[bl * 16 + 12 + jj];
      float cold = sm.cst[tid];
      float cn = sigm(fG) * cold + sigm(iG) * tanh_(gG);
      float hn = sigm(oG) * tanh_(cn);
      sm.cst[tid] = cn;
      hW[(long)bl * 1024 + bk * 4 + jj] = f2bf(hn);
    }
    gsync(p.bar, &sm.ep);
  }
}

extern "C" void kernel_launch(void* const* d_in, const int* in_sizes, int n_in,
                              void* d_out, int out_size, void* d_ws, size_t ws_size,
                              hipStream_t stream) {
  char* p = (char*)d_ws;
  auto carve = [&](size_t bytes) -> char* {
    char* r = p;
    p += (bytes + 255) & ~(size_t)255;
    return r;
  };
  // --- zeroed region: h double-buffers + barrier counters ---
  char* zbase = p;
  u16* h_f = (u16*)carve(2 * 8192 * 2);
  u16* h_b = (u16*)carve(2 * 8192 * 2);
  u16* h_dec = (u16*)carve(2 * 32768 * 2);
  unsigned* bar = (unsigned*)carve(8192);
  size_t zwords = (size_t)(p - zbase) / 4;
  // --- dtype flag + canonical bf16 input copies ---
  int* flag = (int*)carve(256);
  static const int cvn[18] = {
      1024000, 37888, 262144, 262144, 1024, 262144, 262144, 1024,
      1572864, 1024, 1024, 2424832, 4194304, 4096, 81920, 80, 1024, 1 };
  u16* cv[18];
  for (int i = 0; i < 18; ++i) cv[i] = (u16*)carve((size_t)cvn[i] * 2);
  // --- runtime buffers ---
  u16* enc_out = (u16*)carve(3276800ull * 2);
  u16* proj = (u16*)carve(6553600ull * 2);
  float* hp = (float*)carve(32768 * 4);
  float* ctx = (float*)carve(16384 * 4);
  float* sumexp = (float*)carve(64 * 4);

  hipLaunchKernelGGL(k_detect, dim3(1), dim3(256), 0, stream,
                     (const u16*)d_in[2], flag);
  for (int i = 0; i < 18; ++i) {
    int n = in_sizes[i + 1];
    int blocks = (n + 255) / 256; if (blocks > 128) blocks = 128;
    hipLaunchKernelGGL(k_conv, dim3(blocks), dim3(256), 0, stream,
                       (const void*)d_in[i + 1], cv[i], n, (const int*)flag);
  }
  hipLaunchKernelGGL(k_zero, dim3(96), dim3(256), 0, stream,
                     (unsigned int*)zbase, (int)zwords);

  P prm;
  prm.text = (const int*)d_in[0];
  prm.mel = cv[0];   prm.emb = cv[1];
  prm.eWihF = cv[2]; prm.eWhhF = cv[3]; prm.ebF = cv[4];
  prm.eWihB = cv[5]; prm.eWhhB = cv[6]; prm.ebB = cv[7];
  prm.Ws = cv[8];    prm.bs = cv[9];    prm.vv = cv[10];
  prm.dWih = cv[11]; prm.dWhh = cv[12]; prm.db = cv[13];
  prm.Wout = cv[14]; prm.bout = cv[15]; prm.Wstop = cv[16]; prm.bstop = cv[17];
  prm.enc_out = enc_out; prm.proj = proj;
  prm.hp = hp; prm.ctx = ctx; prm.sumexp = sumexp;
  prm.h_f = h_f; prm.h_b = h_b; prm.h_dec = h_dec;
  prm.out = d_out; prm.flag = flag; prm.bar = bar;
  void* kargs[] = { (void*)&prm };
  (void)hipLaunchCooperativeKernel((void*)k_all, dim3(256), dim3(256), kargs, 0, stream);
}

// Round 2
// 11957.131 us; speedup vs baseline: 3.7161x; 2.0723x over previous
//
#include <hip/hip_runtime.h>

typedef unsigned short u16;
typedef short s8v __attribute__((ext_vector_type(8)));
typedef float f4v __attribute__((ext_vector_type(4)));

#define MFMA16 __builtin_amdgcn_mfma_f32_16x16x32_bf16
#define SCOPE_AGENT __HIP_MEMORY_SCOPE_AGENT

// ---------- scalar helpers ----------
__device__ __forceinline__ float bf2f(u16 u) {
  union { unsigned int i; float f; } c; c.i = ((unsigned int)u) << 16; return c.f;
}
__device__ __forceinline__ u16 f2bf(float f) {
  union { float f; unsigned int i; } c; c.f = f;
  unsigned int i = c.i;
  unsigned int r = i + 0x7FFFu + ((i >> 16) & 1u);  // RNE
  return (u16)(r >> 16);
}
__device__ __forceinline__ float sigm(float x) {
  float e = __builtin_amdgcn_exp2f(-1.44269504f * x);
  return __builtin_amdgcn_rcpf(1.0f + e);
}
__device__ __forceinline__ float tanh_(float x) {
  float e = __builtin_amdgcn_exp2f(2.88539009f * x);   // e^(2x)
  return 1.0f - 2.0f * __builtin_amdgcn_rcpf(e + 1.0f);
}
__device__ __forceinline__ void store_out(void* out, int mode, long idx, float v) {
  if (mode) ((float*)out)[idx] = v;
  else      ((u16*)out)[idx] = f2bf(v);
}

// ---------- coherent (agent-scope, fence-free) comm helpers ----------
__device__ __forceinline__ unsigned long long ld64a(const void* p) {
  return __hip_atomic_load((const unsigned long long*)p, __ATOMIC_RELAXED, SCOPE_AGENT);
}
__device__ __forceinline__ s8v ld16a(const void* p) {
  union { unsigned long long u[2]; s8v v; } c;
  c.u[0] = ld64a(p);
  c.u[1] = ld64a((const char*)p + 8);
  return c.v;
}
__device__ __forceinline__ float ldfa(const float* p) {
  return __hip_atomic_load(p, __ATOMIC_RELAXED, SCOPE_AGENT);
}
__device__ __forceinline__ void stfa(float* p, float v) {
  __hip_atomic_store(p, v, __ATOMIC_RELAXED, SCOPE_AGENT);
}
__device__ __forceinline__ void stha(u16* p, u16 v) {
  __hip_atomic_store(p, v, __ATOMIC_RELAXED, SCOPE_AGENT);
}

// ---------- dtype detector ----------
__global__ void k_detect(const u16* __restrict__ raw, int* __restrict__ flag) {
  __shared__ int cnt[256];
  int c = 0;
  for (int j = 0; j < 8; ++j) {
    int i = (threadIdx.x * 8 + j) * 2;
    int e = (raw[i] >> 7) & 0xFF;
    c += (e >= 130);
  }
  cnt[threadIdx.x] = c;
  __syncthreads();
  if (threadIdx.x == 0) {
    int s = 0;
    for (int i = 0; i < 256; ++i) s += cnt[i];
    *flag = (s > 64) ? 1 : 0;
  }
}

// ---------- normalize input to bf16 ----------
__global__ void k_conv(const void* __restrict__ src, u16* __restrict__ dst,
                       int n, const int* __restrict__ flag) {
  int mode = *flag;
  int i = blockIdx.x * blockDim.x + threadIdx.x;
  int st = gridDim.x * blockDim.x;
  if (mode) {
    const float* s = (const float*)src;
    for (; i < n; i += st) dst[i] = f2bf(s[i]);
  } else {
    const u16* s = (const u16*)src;
    for (; i < n; i += st) dst[i] = s[i];
  }
}

// ---------- zero init ----------
__global__ void k_zero(unsigned int* p, int n) {
  int i = blockIdx.x * blockDim.x + threadIdx.x;
  int st = gridDim.x * blockDim.x;
  for (; i < n; i += st) p[i] = 0u;
}

// ---------- device-wide barrier (2-level). Light: no L2 wb/inv (comm data is
// agent-coherent; __syncthreads drains each wave's VMEM before s_barrier).
// Heavy (2 uses): __threadfence publishes plain-stored write-once buffers. ----
__device__ __forceinline__ void gsync(unsigned* bar, unsigned* sep, bool heavy) {
  __syncthreads();
  if (threadIdx.x == 0) {
    unsigned e = *sep;
    if (heavy) __threadfence();
    unsigned* leaf = bar + 128 + ((blockIdx.x & 15) << 6);
    if (__hip_atomic_fetch_add(leaf, 1u, __ATOMIC_RELAXED, SCOPE_AGENT) == e * 16u + 15u) {
      if (__hip_atomic_fetch_add(bar + 64, 1u, __ATOMIC_RELAXED, SCOPE_AGENT) == e * 16u + 15u)
        __hip_atomic_fetch_add(bar, 1u, __ATOMIC_RELAXED, SCOPE_AGENT);
    }
    while (__hip_atomic_load(bar, __ATOMIC_RELAXED, SCOPE_AGENT) <= e)
      __builtin_amdgcn_s_sleep(1);
    *sep = e + 1;
    if (heavy) __threadfence();
    asm volatile("" ::: "memory");
  }
  __syncthreads();
}

// ---------- persistent-kernel shared state (~151 KB of 160 KB) ----------
struct __align__(16) SMem {
  u16 W[26112];      // 52224B: dec gate-weight slice, fragment-major (enc overlay)
  u16 proj[25600];   // 51200B: this block's 25-row proj slice
  u16 wsd[16384];    // 32768B: Ws_dec / Wout col-tile (blocks 0-68), Wstop (69)
  u16 v[1024];       //  2048B
  float hp[1024];    //  4096B
  float exl[32];     //   128B
  float gsc[2048];   //  8192B: 4-wave K-split partial sums
  float cst[128];    //   512B: LSTM c-state
  unsigned ep;
};

struct P {
  const int* text;
  const u16 *emb, *eWihF, *eWhhF, *ebF, *eWihB, *eWhhB, *ebB;
  const u16 *Ws, *bs, *vv, *dWih, *dWhh, *db, *Wout, *bout, *Wstop, *bstop, *mel;
  u16 *enc_out, *proj;
  float *hp, *ctx, *sumexp;
  u16 *h_f, *h_b, *h_dec;
  void* out;
  const int* flag;
  unsigned* bar;
};

__global__ void __launch_bounds__(256, 1) k_all(P p) {
  __shared__ SMem sm;
  const int tid = threadIdx.x;
  const int bk = blockIdx.x;
  const int lane = tid & 63;
  const int wv = tid >> 6;
  const int q = lane >> 4, l15 = lane & 15;
  const s8v zero8 = {0, 0, 0, 0, 0, 0, 0, 0};
  if (tid == 0) sm.ep = 0;
  const int mode = *p.flag;

  // ================= encoder: block = (dir, mtile, 4-col group) =================
  const int dirE = bk >> 7;
  const int mtE = (bk >> 6) & 1;
  const int j0E = (bk & 63) * 4;
  {
    const u16* Wih = dirE ? p.eWihB : p.eWihF;
    const u16* Whh = dirE ? p.eWhhB : p.eWhhF;
    for (int i = tid; i < 1024; i += 256) {            // 64 frags x 16 rows
      int f = i >> 4, nl = i & 15;
      int row = (nl >> 2) * 256 + j0E + (nl & 3);      // gate*256 + col
      int k = f * 8;
      const u16* src = (k < 256) ? (Wih + row * 256 + k) : (Whh + row * 256 + k - 256);
      *(s8v*)(sm.W + (size_t)i * 8) = *(const s8v*)src;
    }
    if (tid < 64) sm.cst[tid] = 0.f;
  }
  float ebias;
  {
    const u16* eb = dirE ? p.ebB : p.ebF;
    ebias = bf2f(eb[(l15 >> 2) * 256 + j0E + (l15 & 3)]);
  }
  __syncthreads();
  {
    u16* hbuf = dirE ? p.h_b : p.h_f;
    for (int stp = 0; stp < 200; ++stp) {
      int tb = dirE ? (199 - stp) : stp;
      const u16* hR = hbuf + (stp & 1) * 8192;
      u16* hW = hbuf + ((stp + 1) & 1) * 8192;
      {
        int m = mtE * 16 + l15;
        const u16* xrow = p.emb + (long)p.text[m * 200 + tb] * 256;
        const u16* hrow = hR + m * 256;
        f4v acc;
        float b0 = (wv == 0) ? ebias : 0.f;
        acc[0] = b0; acc[1] = b0; acc[2] = b0; acc[3] = b0;
#pragma unroll
        for (int i = 0; i < 4; ++i) {                  // K split over 4 waves
          int kc = wv * 4 + i;
          int k8 = kc * 32 + q * 8;
          s8v a = (k8 < 256) ? *(const s8v*)(xrow + k8) : ld16a(hrow + (k8 - 256));
          s8v b = *(const s8v*)(sm.W + (size_t)((kc * 4 + q) * 16 + l15) * 8);
          acc = MFMA16(a, b, acc, 0, 0, 0);
        }
#pragma unroll
        for (int r = 0; r < 4; ++r) sm.gsc[wv * 256 + (q * 4 + r) * 16 + l15] = acc[r];
      }
      __syncthreads();
      if (tid < 64) {
        int bl = tid >> 2, jj = tid & 3;
        float iG = 0.f, fG = 0.f, gG = 0.f, oG = 0.f;
#pragma unroll
        for (int w = 0; w < 4; ++w) {
          const float* g = sm.gsc + w * 256 + bl * 16;
          iG += g[jj]; fG += g[4 + jj]; gG += g[8 + jj]; oG += g[12 + jj];
        }
        float cold = sm.cst[tid];
        float cn = sigm(fG) * cold + sigm(iG) * tanh_(gG);
        float hn = sigm(oG) * tanh_(cn);
        sm.cst[tid] = cn;
        u16 hb16 = f2bf(hn);
        int b = mtE * 16 + bl;
        int col = j0E + jj;
        stha(&hW[b * 256 + col], hb16);
        p.enc_out[((long)b * 200 + tb) * 512 + dirE * 256 + col] = hb16;  // plain; heavy fence below
      }
      gsync(p.bar, &sm.ep, stp == 199);
    }
  }

  // ================= proj = enc_out @ Ws_enc^T + bs =================
  {
    int w = bk * 4 + wv;
    for (int j = 0; j < 25; ++j) {
      int job = w * 25 + j;
      int mt = job >> 6, nt = job & 63;
      int m = mt * 16 + l15;
      const u16* arow = p.enc_out + (long)m * 512;
      int n = nt * 16 + l15;
      const u16* brow = p.Ws + (long)n * 1536;
      f4v acc = {0.f, 0.f, 0.f, 0.f};
#pragma unroll
      for (int kc = 0; kc < 16; ++kc) {
        s8v a = *(const s8v*)(arow + kc * 32 + q * 8);
        s8v b = *(const s8v*)(brow + kc * 32 + q * 8);
        acc = MFMA16(a, b, acc, 0, 0, 0);
      }
      float bias = bf2f(p.bs[n]);
#pragma unroll
      for (int r = 0; r < 4; ++r)
        p.proj[(long)(mt * 16 + q * 4 + r) * 1024 + n] = f2bf(acc[r] + bias);
    }
  }
  gsync(p.bar, &sm.ep, true);

  // ================= decoder staging (all LDS-local) =================
  const int bA = bk >> 3, s0A = (bk & 7) * 25;
  float dbias;
  {
    int j0 = bk * 4;
    for (int i = tid; i < 3264; i += 256) {             // 204 frags x 16 rows
      int f = i >> 4, nl = i & 15;
      long row = (long)(nl >> 2) * 1024 + j0 + (nl & 3);
      int k = f * 8;
      s8v val;
      if (k < 592)       val = *(const s8v*)(p.dWih + row * 592 + k);
      else if (k < 1616) val = *(const s8v*)(p.dWhh + row * 1024 + k - 592);
      else               val = zero8;
      *(s8v*)(sm.W + (size_t)i * 8) = val;
    }
    dbias = bf2f(p.db[(l15 >> 2) * 1024 + j0 + (l15 & 3)]);
    if (bk < 69) {
      const u16* base = (bk < 64) ? (p.Ws + 512) : p.Wout;
      long rstr = (bk < 64) ? 1536 : 1024;
      long r0 = (bk < 64) ? bk * 16 : (long)(bk - 64) * 16;
      for (int i = tid; i < 2048; i += 256) {           // 128 frags x 16 rows
        int f = i >> 4, nl = i & 15;
        *(s8v*)(sm.wsd + (size_t)i * 8) = *(const s8v*)(base + (r0 + nl) * rstr + f * 8);
      }
    } else if (bk == 69) {
      if (tid < 128) *(s8v*)(sm.wsd + tid * 8) = *(const s8v*)(p.Wstop + tid * 8);
    }
    const u16* psrc = p.proj + (long)(bA * 200 + s0A) * 1024;
    for (int i = tid * 8; i < 25600; i += 2048)
      *(s8v*)(sm.proj + i) = *(const s8v*)(psrc + i);
    if (tid < 128) *(s8v*)(sm.v + tid * 8) = *(const s8v*)(p.vv + tid * 8);
    if (tid < 128) sm.cst[tid] = 0.f;
  }
  __syncthreads();

  // ================= decoder loop: 3 light barriers/step =================
  for (int t = 0; t <= 400; ++t) {
    const u16* hR = p.h_dec + (t & 1) * 32768;
    u16* hW = p.h_dec + ((t + 1) & 1) * 32768;
    // ---- phase H: hp / mel(t-1) / stop(t-1) / zero ctx+sumexp ----
    if (bk < 64) {
      if (t < 400) {
        int mtile = wv & 1, khalf = wv >> 1;
        int m = mtile * 16 + l15;
        const u16* arow = hR + m * 1024;
        f4v acc = {0.f, 0.f, 0.f, 0.f};
#pragma unroll
        for (int i = 0; i < 16; ++i) {                  // K=1024 split 2 ways
          int kc = khalf * 16 + i;
          s8v a = ld16a(arow + kc * 32 + q * 8);
          s8v b = *(const s8v*)(sm.wsd + (size_t)((kc * 4 + q) * 16 + l15) * 8);
          acc = MFMA16(a, b, acc, 0, 0, 0);
        }
#pragma unroll
        for (int r = 0; r < 4; ++r) sm.gsc[wv * 512 + (q * 4 + r) * 16 + l15] = acc[r];
        __syncthreads();
        for (int oi = tid; oi < 512; oi += 256) {
          int mt2 = oi >> 8, idx = oi & 255;
          float val = sm.gsc[mt2 * 512 + idx] + sm.gsc[1024 + mt2 * 512 + idx];
          int mrow = mt2 * 16 + (idx >> 4);
          int n = bk * 16 + (idx & 15);
          stfa(&p.hp[mrow * 1024 + n], val);
        }
      }
    } else if (bk < 69) {
      if (t > 0) {
        int mtile = wv & 1, khalf = wv >> 1;
        int m = mtile * 16 + l15;
        const u16* arow = hR + m * 1024;
        f4v acc = {0.f, 0.f, 0.f, 0.f};
#pragma unroll
        for (int i = 0; i < 16; ++i) {
          int kc = khalf * 16 + i;
          s8v a = ld16a(arow + kc * 32 + q * 8);
          s8v b = *(const s8v*)(sm.wsd + (size_t)((kc * 4 + q) * 16 + l15) * 8);
          acc = MFMA16(a, b, acc, 0, 0, 0);
        }
#pragma unroll
        for (int r = 0; r < 4; ++r) sm.gsc[wv * 512 + (q * 4 + r) * 16 + l15] = acc[r];
        __syncthreads();
        for (int oi = tid; oi < 512; oi += 256) {
          int mt2 = oi >> 8, idx = oi & 255;
          float val = sm.gsc[mt2 * 512 + idx] + sm.gsc[1024 + mt2 * 512 + idx];
          int mrow = mt2 * 16 + (idx >> 4);
          int n = (bk - 64) * 16 + (idx & 15);
          store_out(p.out, mode, ((long)mrow * 400 + (t - 1)) * 80 + n,
                    val + bf2f(p.bout[n]));
        }
      }
    } else if (bk == 69) {
      if (t > 0) {
        int b = tid >> 3, kp = tid & 7;
        const u16* hrow = hR + b * 1024 + kp * 128;
        float s = 0.f;
#pragma unroll 8
        for (int k = 0; k < 32; ++k) {                  // 128 u16 as 32x8B coherent
          union { unsigned long long u; u16 h[4]; } cu;
          cu.u = ld64a(hrow + k * 4);
#pragma unroll
          for (int j = 0; j < 4; ++j)
            s += bf2f(cu.h[j]) * bf2f(sm.wsd[kp * 128 + k * 4 + j]);
        }
        s += __shfl_xor(s, 1, 64);
        s += __shfl_xor(s, 2, 64);
        s += __shfl_xor(s, 4, 64);
        if (kp == 0)
          store_out(p.out, mode, 1024000 + (long)b * 400 + (t - 1),
                    sigm(s + bf2f(p.bstop[0])));
      }
    } else if (bk < 134) {
      stfa(&p.ctx[(bk - 70) * 256 + tid], 0.f);
    } else if (bk == 134) {
      if (tid < 32) stfa(&p.sumexp[tid], 0.f);
    }
    if (t == 400) break;
    gsync(p.bar, &sm.ep, false);

    // ---- phase A: attention for (bA, 25 positions) ----
    for (int i = tid; i < 1024; i += 256) sm.hp[i] = ldfa(&p.hp[bA * 1024 + i]);
    __syncthreads();
    {
      f4v h0a = *(const f4v*)(sm.hp + lane * 8);
      f4v h0b = *(const f4v*)(sm.hp + lane * 8 + 4);
      f4v h1a = *(const f4v*)(sm.hp + 512 + lane * 8);
      f4v h1b = *(const f4v*)(sm.hp + 512 + lane * 8 + 4);
      s8v v0 = *(const s8v*)(sm.v + lane * 8);
      s8v v1 = *(const s8v*)(sm.v + 512 + lane * 8);
      for (int si = wv; si < 25; si += 4) {
        const u16* prow = sm.proj + si * 1024;
        s8v p0 = *(const s8v*)(prow + lane * 8);
        s8v p1 = *(const s8v*)(prow + 512 + lane * 8);
        float part = 0.f;
#pragma unroll
        for (int jj = 0; jj < 4; ++jj) {
          part += tanh_(bf2f((u16)p0[jj]) + h0a[jj]) * bf2f((u16)v0[jj]);
          part += tanh_(bf2f((u16)p0[jj + 4]) + h0b[jj]) * bf2f((u16)v0[jj + 4]);
          part += tanh_(bf2f((u16)p1[jj]) + h1a[jj]) * bf2f((u16)v1[jj]);
          part += tanh_(bf2f((u16)p1[jj + 4]) + h1b[jj]) * bf2f((u16)v1[jj + 4]);
        }
#pragma unroll
        for (int off = 32; off >= 1; off >>= 1) part += __shfl_xor(part, off, 64);
        if (lane == 0) sm.exl[si] = __builtin_amdgcn_exp2f(1.44269504f * part);
      }
    }
    __syncthreads();
    if (tid == 0) {
      float ss = 0.f;
      for (int i = 0; i < 25; ++i) ss += sm.exl[i];
      atomicAdd(&p.sumexp[bA], ss);
    }
    {
      int e0 = tid * 2;
      float a0 = 0.f, a1 = 0.f;
      const u16* eb = p.enc_out + (long)(bA * 200 + s0A) * 512 + e0;  // plain: immutable, L2-hot
#pragma unroll 5
      for (int i = 0; i < 25; ++i) {
        float w = sm.exl[i];
        unsigned pr = *(const unsigned*)(eb + (size_t)i * 512);
        a0 += w * bf2f((u16)(pr & 0xffffu));
        a1 += w * bf2f((u16)(pr >> 16));
      }
      atomicAdd(&p.ctx[bA * 512 + e0], a0);
      atomicAdd(&p.ctx[bA * 512 + e0 + 1], a1);
    }
    gsync(p.bar, &sm.ep, false);

    // ---- phase G: gates GEMM (K=1632, 4-wave K-split) + LSTM cell + aligns ----
    {
      int mtile = wv & 1, khalf = wv >> 1;
      int m = mtile * 16 + l15;
      float rsm = __builtin_amdgcn_rcpf(ldfa(&p.sumexp[m]));
      const u16* melrow = p.mel + ((long)m * 400 + (t - 1)) * 80;
      const u16* hrow = hR + m * 1024;
      const float* crow = p.ctx + m * 512;
      f4v acc;
      float b0 = (khalf == 0) ? dbias : 0.f;
      acc[0] = b0; acc[1] = b0; acc[2] = b0; acc[3] = b0;
      for (int kc = khalf; kc < 51; kc += 2) {
        int k8 = kc * 32 + q * 8;
        s8v a;
        if (k8 < 80) {
          a = (t == 0) ? zero8 : *(const s8v*)(melrow + k8);
        } else if (k8 < 592) {
          const float* cr = crow + (k8 - 80);
          union { unsigned long long u[4]; float f[8]; } cu;
          cu.u[0] = ld64a(cr);     cu.u[1] = ld64a(cr + 2);
          cu.u[2] = ld64a(cr + 4); cu.u[3] = ld64a(cr + 6);
          s8v t8;
#pragma unroll
          for (int jj = 0; jj < 8; ++jj) t8[jj] = (short)f2bf(cu.f[jj] * rsm);
          a = t8;
        } else if (k8 < 1616) {
          a = ld16a(hrow + (k8 - 592));
        } else {
          a = zero8;
        }
        s8v b = *(const s8v*)(sm.W + (size_t)((kc * 4 + q) * 16 + l15) * 8);
        acc = MFMA16(a, b, acc, 0, 0, 0);
      }
#pragma unroll
      for (int r = 0; r < 4; ++r) sm.gsc[wv * 512 + (q * 4 + r) * 16 + l15] = acc[r];
    }
    __syncthreads();
    if (tid < 128) {
      int bl = tid >> 2, jj = tid & 3;
      int mt2 = bl >> 4;
      const float* g0 = sm.gsc + mt2 * 512 + (bl & 15) * 16;
      const float* g1 = g0 + 1024;
      float iG = g0[jj] + g1[jj];
      float fG = g0[4 + jj] + g1[4 + jj];
      float gG = g0[8 + jj] + g1[8 + jj];
      float oG = g0[12 + jj] + g1[12 + jj];
      float cold = sm.cst[tid];
      float cn = sigm(fG) * cold + sigm(iG) * tanh_(gG);
      float hn = sigm(oG) * tanh_(cn);
      sm.cst[tid] = cn;
      stha(&hW[(long)bl * 1024 + bk * 4 + jj], f2bf(hn));
    } else if (tid >= 192 && tid < 217) {
      int sl = tid - 192;
      float rs = __builtin_amdgcn_rcpf(ldfa(&p.sumexp[bA]));
      store_out(p.out, mode, 1036800 + ((long)bA * 400 + t) * 200 + s0A + sl,
                sm.exl[sl] * rs);
    }
    gsync(p.bar, &sm.ep, false);
  }
}

extern "C" void kernel_launch(void* const* d_in, const int* in_sizes, int n_in,
                              void* d_out, int out_size, void* d_ws, size_t ws_size,
                              hipStream_t stream) {
  char* p = (char*)d_ws;
  auto carve = [&](size_t bytes) -> char* {
    char* r = p;
    p += (bytes + 255) & ~(size_t)255;
    return r;
  };
  // --- zeroed region: h double-buffers + barrier counters ---
  char* zbase = p;
  u16* h_f = (u16*)carve(2 * 8192 * 2);
  u16* h_b = (u16*)carve(2 * 8192 * 2);
  u16* h_dec = (u16*)carve(2 * 32768 * 2);
  unsigned* bar = (unsigned*)carve(8192);
  size_t zwords = (size_t)(p - zbase) / 4;
  // --- dtype flag + canonical bf16 input copies ---
  int* flag = (int*)carve(256);
  static const int cvn[18] = {
      1024000, 37888, 262144, 262144, 1024, 262144, 262144, 1024,
      1572864, 1024, 1024, 2424832, 4194304, 4096, 81920, 80, 1024, 1 };
  u16* cv[18];
  for (int i = 0; i < 18; ++i) cv[i] = (u16*)carve((size_t)cvn[i] * 2);
  // --- runtime buffers ---
  u16* enc_out = (u16*)carve(3276800ull * 2);
  u16* proj = (u16*)carve(6553600ull * 2);
  float* hp = (float*)carve(32768 * 4);
  float* ctx = (float*)carve(16384 * 4);
  float* sumexp = (float*)carve(64 * 4);

  hipLaunchKernelGGL(k_detect, dim3(1), dim3(256), 0, stream,
                     (const u16*)d_in[2], flag);
  for (int i = 0; i < 18; ++i) {
    int n = in_sizes[i + 1];
    int blocks = (n + 255) / 256; if (blocks > 128) blocks = 128;
    hipLaunchKernelGGL(k_conv, dim3(blocks), dim3(256), 0, stream,
                       (const void*)d_in[i + 1], cv[i], n, (const int*)flag);
  }
  hipLaunchKernelGGL(k_zero, dim3(96), dim3(256), 0, stream,
                     (unsigned int*)zbase, (int)zwords);

  P prm;
  prm.text = (const int*)d_in[0];
  prm.mel = cv[0];   prm.emb = cv[1];
  prm.eWihF = cv[2]; prm.eWhhF = cv[3]; prm.ebF = cv[4];
  prm.eWihB = cv[5]; prm.eWhhB = cv[6]; prm.ebB = cv[7];
  prm.Ws = cv[8];    prm.bs = cv[9];    prm.vv = cv[10];
  prm.dWih = cv[11]; prm.dWhh = cv[12]; prm.db = cv[13];
  prm.Wout = cv[14]; prm.bout = cv[15]; prm.Wstop = cv[16]; prm.bstop = cv[17];
  prm.enc_out = enc_out; prm.proj = proj;
  prm.hp = hp; prm.ctx = ctx; prm.sumexp = sumexp;
  prm.h_f = h_f; prm.h_b = h_b; prm.h_dec = h_dec;
  prm.out = d_out; prm.flag = flag; prm.bar = bar;
  void* kargs[] = { (void*)&prm };
  (void)hipLaunchCooperativeKernel((void*)k_all, dim3(256), dim3(256), kargs, 0, stream);
}

// Round 7
// 11852.491 us; speedup vs baseline: 3.7489x; 1.0088x over previous
//
#include <hip/hip_runtime.h>

typedef unsigned short u16;
typedef short s8v __attribute__((ext_vector_type(8)));
typedef float f4v __attribute__((ext_vector_type(4)));

#define MFMA16 __builtin_amdgcn_mfma_f32_16x16x32_bf16
#define SCOPE_AGENT __HIP_MEMORY_SCOPE_AGENT

// ---------- scalar helpers ----------
__device__ __forceinline__ float bf2f(u16 u) {
  union { unsigned int i; float f; } c; c.i = ((unsigned int)u) << 16; return c.f;
}
__device__ __forceinline__ u16 f2bf(float f) {
  union { float f; unsigned int i; } c; c.f = f;
  unsigned int i = c.i;
  unsigned int r = i + 0x7FFFu + ((i >> 16) & 1u);  // RNE
  return (u16)(r >> 16);
}
__device__ __forceinline__ float sigm(float x) {
  float e = __builtin_amdgcn_exp2f(-1.44269504f * x);
  return __builtin_amdgcn_rcpf(1.0f + e);
}
__device__ __forceinline__ float tanh_(float x) {
  float e = __builtin_amdgcn_exp2f(2.88539009f * x);   // e^(2x)
  return 1.0f - 2.0f * __builtin_amdgcn_rcpf(e + 1.0f);
}
__device__ __forceinline__ void store_out(void* out, int mode, long idx, float v) {
  if (mode) ((float*)out)[idx] = v;
  else      ((u16*)out)[idx] = f2bf(v);
}

// ---------- coherent (agent-scope, fence-free) comm helpers ----------
__device__ __forceinline__ unsigned long long ld64a(const void* p) {
  return __hip_atomic_load((const unsigned long long*)p, __ATOMIC_RELAXED, SCOPE_AGENT);
}
__device__ __forceinline__ s8v ld16a(const void* p) {
  union { unsigned long long u[2]; s8v v; } c;
  c.u[0] = ld64a(p);
  c.u[1] = ld64a((const char*)p + 8);
  return c.v;
}
__device__ __forceinline__ float ldfa(const float* p) {
  return __hip_atomic_load(p, __ATOMIC_RELAXED, SCOPE_AGENT);
}
__device__ __forceinline__ void stfa(float* p, float v) {
  __hip_atomic_store(p, v, __ATOMIC_RELAXED, SCOPE_AGENT);
}
__device__ __forceinline__ void stha(u16* p, u16 v) {
  __hip_atomic_store(p, v, __ATOMIC_RELAXED, SCOPE_AGENT);
}

// ---------- dtype detector ----------
__global__ void k_detect(const u16* __restrict__ raw, int* __restrict__ flag) {
  __shared__ int cnt[256];
  int c = 0;
  for (int j = 0; j < 8; ++j) {
    int i = (threadIdx.x * 8 + j) * 2;
    int e = (raw[i] >> 7) & 0xFF;
    c += (e >= 130);
  }
  cnt[threadIdx.x] = c;
  __syncthreads();
  if (threadIdx.x == 0) {
    int s = 0;
    for (int i = 0; i < 256; ++i) s += cnt[i];
    *flag = (s > 64) ? 1 : 0;
  }
}

// ---------- normalize input to bf16 ----------
__global__ void k_conv(const void* __restrict__ src, u16* __restrict__ dst,
                       int n, const int* __restrict__ flag) {
  int mode = *flag;
  int i = blockIdx.x * blockDim.x + threadIdx.x;
  int st = gridDim.x * blockDim.x;
  if (mode) {
    const float* s = (const float*)src;
    for (; i < n; i += st) dst[i] = f2bf(s[i]);
  } else {
    const u16* s = (const u16*)src;
    for (; i < n; i += st) dst[i] = s[i];
  }
}

// ---------- zero init ----------
__global__ void k_zero(unsigned int* p, int n) {
  int i = blockIdx.x * blockDim.x + threadIdx.x;
  int st = gridDim.x * blockDim.x;
  for (; i < n; i += st) p[i] = 0u;
}

// ---------- device-wide barrier (2-level). Light: no L2 wb/inv (comm data is
// agent-coherent; __syncthreads drains each wave's VMEM before s_barrier).
// Heavy (2 uses): __threadfence publishes plain-stored write-once buffers. ----
__device__ __forceinline__ void gsync(unsigned* bar, unsigned* sep, bool heavy) {
  __syncthreads();
  if (threadIdx.x == 0) {
    unsigned e = *sep;
    if (heavy) __threadfence();
    unsigned* leaf = bar + 128 + ((blockIdx.x & 15) << 6);
    if (__hip_atomic_fetch_add(leaf, 1u, __ATOMIC_RELAXED, SCOPE_AGENT) == e * 16u + 15u) {
      if (__hip_atomic_fetch_add(bar + 64, 1u, __ATOMIC_RELAXED, SCOPE_AGENT) == e * 16u + 15u)
        __hip_atomic_fetch_add(bar, 1u, __ATOMIC_RELAXED, SCOPE_AGENT);
    }
    while (__hip_atomic_load(bar, __ATOMIC_RELAXED, SCOPE_AGENT) <= e)
      __builtin_amdgcn_s_sleep(1);
    *sep = e + 1;
    if (heavy) __threadfence();
    asm volatile("" ::: "memory");
  }
  __syncthreads();
}

// ---------- persistent-kernel shared state (~151 KB) ----------
struct __align__(16) SMem {
  u16 W[26112];      // 52224B: dec gate-weight slice, fragment-major (enc overlay)
  u16 proj[25600];   // 51200B: this block's 25-row proj slice
  u16 wsd[16384];    // 32768B: Ws_dec / Wout col-tile (blocks 0-68), Wstop (69)
  u16 v[1024];       //  2048B
  float hp[1024];    //  4096B
  float exl[32];     //   128B
  float gsc[2048];   //  8192B: 4-wave K-split partial sums
  float cst[128];    //   512B: LSTM c-state
  unsigned ep;
};

struct P {
  const int* text;
  const u16 *emb, *eWihF, *eWhhF, *ebF, *eWihB, *eWhhB, *ebB;
  const u16 *Ws, *bs, *vv, *dWih, *dWhh, *db, *Wout, *bout, *Wstop, *bstop, *mel;
  u16 *enc_out, *proj;
  float *hp, *ctx, *sumexp;
  u16 *h_f, *h_b, *h_dec;
  void* out;
  const int* flag;
  unsigned* bar;
};

__global__ void __launch_bounds__(256, 1) k_all(P p) {
  __shared__ SMem sm;
  const int tid = threadIdx.x;
  const int bk = blockIdx.x;
  const int lane = tid & 63;
  const int wv = tid >> 6;
  const int q = lane >> 4, l15 = lane & 15;
  const s8v zero8 = {0, 0, 0, 0, 0, 0, 0, 0};
  if (tid == 0) sm.ep = 0;
  const int mode = *p.flag;

  // ================= encoder: block = (dir, mtile, 4-col group) =================
  const int dirE = bk >> 7;
  const int mtE = (bk >> 6) & 1;
  const int j0E = (bk & 63) * 4;
  {
    const u16* Wih = dirE ? p.eWihB : p.eWihF;
    const u16* Whh = dirE ? p.eWhhB : p.eWhhF;
    for (int i = tid; i < 1024; i += 256) {            // 64 frags x 16 rows
      int f = i >> 4, nl = i & 15;
      int row = (nl >> 2) * 256 + j0E + (nl & 3);      // gate*256 + col
      int k = f * 8;
      const u16* src = (k < 256) ? (Wih + row * 256 + k) : (Whh + row * 256 + k - 256);
      *(s8v*)(sm.W + (size_t)i * 8) = *(const s8v*)src;
    }
    if (tid < 64) sm.cst[tid] = 0.f;
  }
  float ebias;
  {
    const u16* eb = dirE ? p.ebB : p.ebF;
    ebias = bf2f(eb[(l15 >> 2) * 256 + j0E + (l15 & 3)]);
  }
  __syncthreads();
  {
    u16* hbuf = dirE ? p.h_b : p.h_f;
    for (int stp = 0; stp < 200; ++stp) {
      int tb = dirE ? (199 - stp) : stp;
      const u16* hR = hbuf + (stp & 1) * 8192;
      u16* hW = hbuf + ((stp + 1) & 1) * 8192;
      {
        int m = mtE * 16 + l15;
        const u16* xrow = p.emb + (long)p.text[m * 200 + tb] * 256;
        const u16* hrow = hR + m * 256;
        f4v acc;
        float b0 = (wv == 0) ? ebias : 0.f;
        acc[0] = b0; acc[1] = b0; acc[2] = b0; acc[3] = b0;
#pragma unroll
        for (int i = 0; i < 4; ++i) {                  // K split over 4 waves
          int kc = wv * 4 + i;
          int k8 = kc * 32 + q * 8;
          s8v a = (k8 < 256) ? *(const s8v*)(xrow + k8) : ld16a(hrow + (k8 - 256));
          s8v b = *(const s8v*)(sm.W + (size_t)((kc * 4 + q) * 16 + l15) * 8);
          acc = MFMA16(a, b, acc, 0, 0, 0);
        }
#pragma unroll
        for (int r = 0; r < 4; ++r) sm.gsc[wv * 256 + (q * 4 + r) * 16 + l15] = acc[r];
      }
      __syncthreads();
      if (tid < 64) {
        int bl = tid >> 2, jj = tid & 3;
        float iG = 0.f, fG = 0.f, gG = 0.f, oG = 0.f;
#pragma unroll
        for (int w = 0; w < 4; ++w) {
          const float* g = sm.gsc + w * 256 + bl * 16;
          iG += g[jj]; fG += g[4 + jj]; gG += g[8 + jj]; oG += g[12 + jj];
        }
        float cold = sm.cst[tid];
        float cn = sigm(fG) * cold + sigm(iG) * tanh_(gG);
        float hn = sigm(oG) * tanh_(cn);
        sm.cst[tid] = cn;
        u16 hb16 = f2bf(hn);
        int b = mtE * 16 + bl;
        int col = j0E + jj;
        stha(&hW[b * 256 + col], hb16);
        p.enc_out[((long)b * 200 + tb) * 512 + dirE * 256 + col] = hb16;  // plain; heavy fence below
      }
      gsync(p.bar, &sm.ep, stp == 199);
    }
  }

  // ================= proj = enc_out @ Ws_enc^T + bs =================
  {
    int w = bk * 4 + wv;
    for (int j = 0; j < 25; ++j) {
      int job = w * 25 + j;
      int mt = job >> 6, nt = job & 63;
      int m = mt * 16 + l15;
      const u16* arow = p.enc_out + (long)m * 512;
      int n = nt * 16 + l15;
      const u16* brow = p.Ws + (long)n * 1536;
      f4v acc = {0.f, 0.f, 0.f, 0.f};
#pragma unroll
      for (int kc = 0; kc < 16; ++kc) {
        s8v a = *(const s8v*)(arow + kc * 32 + q * 8);
        s8v b = *(const s8v*)(brow + kc * 32 + q * 8);
        acc = MFMA16(a, b, acc, 0, 0, 0);
      }
      float bias = bf2f(p.bs[n]);
#pragma unroll
      for (int r = 0; r < 4; ++r)
        p.proj[(long)(mt * 16 + q * 4 + r) * 1024 + n] = f2bf(acc[r] + bias);
    }
  }
  gsync(p.bar, &sm.ep, true);

  // ================= decoder staging (all LDS-local) =================
  const int bA = bk >> 3, s0A = (bk & 7) * 25;
  float dbias;
  {
    int j0 = bk * 4;
    for (int i = tid; i < 3264; i += 256) {             // 204 frags x 16 rows
      int f = i >> 4, nl = i & 15;
      long row = (long)(nl >> 2) * 1024 + j0 + (nl & 3);
      int k = f * 8;
      s8v val;
      if (k < 592)       val = *(const s8v*)(p.dWih + row * 592 + k);
      else if (k < 1616) val = *(const s8v*)(p.dWhh + row * 1024 + k - 592);
      else               val = zero8;
      *(s8v*)(sm.W + (size_t)i * 8) = val;
    }
    dbias = bf2f(p.db[(l15 >> 2) * 1024 + j0 + (l15 & 3)]);
    if (bk < 69) {
      const u16* base = (bk < 64) ? (p.Ws + 512) : p.Wout;
      long rstr = (bk < 64) ? 1536 : 1024;
      long r0 = (bk < 64) ? bk * 16 : (long)(bk - 64) * 16;
      for (int i = tid; i < 2048; i += 256) {           // 128 frags x 16 rows
        int f = i >> 4, nl = i & 15;
        *(s8v*)(sm.wsd + (size_t)i * 8) = *(const s8v*)(base + (r0 + nl) * rstr + f * 8);
      }
    } else if (bk == 69) {
      if (tid < 128) *(s8v*)(sm.wsd + tid * 8) = *(const s8v*)(p.Wstop + tid * 8);
    }
    const u16* psrc = p.proj + (long)(bA * 200 + s0A) * 1024;
    for (int i = tid * 8; i < 25600; i += 2048)
      *(s8v*)(sm.proj + i) = *(const s8v*)(psrc + i);
    if (tid < 128) *(s8v*)(sm.v + tid * 8) = *(const s8v*)(p.vv + tid * 8);
    if (tid < 128) sm.cst[tid] = 0.f;
  }
  __syncthreads();

  // ================= decoder loop: 3 light barriers/step =================
  for (int t = 0; t <= 400; ++t) {
    const u16* hR = p.h_dec + (t & 1) * 32768;
    u16* hW = p.h_dec + ((t + 1) & 1) * 32768;
    // ---- phase H: hp / mel(t-1) / stop(t-1) / zero ctx+sumexp ----
    if (bk < 64) {
      if (t < 400) {
        int mtile = wv & 1, khalf = wv >> 1;
        int m = mtile * 16 + l15;
        const u16* arow = hR + m * 1024;
        f4v acc = {0.f, 0.f, 0.f, 0.f};
#pragma unroll
        for (int i = 0; i < 16; ++i) {                  // K=1024 split 2 ways
          int kc = khalf * 16 + i;
          s8v a = ld16a(arow + kc * 32 + q * 8);
          s8v b = *(const s8v*)(sm.wsd + (size_t)((kc * 4 + q) * 16 + l15) * 8);
          acc = MFMA16(a, b, acc, 0, 0, 0);
        }
#pragma unroll
        for (int r = 0; r < 4; ++r) sm.gsc[wv * 512 + (q * 4 + r) * 16 + l15] = acc[r];
        __syncthreads();
        for (int oi = tid; oi < 512; oi += 256) {
          int mt2 = oi >> 8, idx = oi & 255;
          float val = sm.gsc[mt2 * 512 + idx] + sm.gsc[1024 + mt2 * 512 + idx];
          int mrow = mt2 * 16 + (idx >> 4);
          int n = bk * 16 + (idx & 15);
          stfa(&p.hp[mrow * 1024 + n], val);
        }
      }
    } else if (bk < 69) {
      if (t > 0) {
        int mtile = wv & 1, khalf = wv >> 1;
        int m = mtile * 16 + l15;
        const u16* arow = hR + m * 1024;
        f4v acc = {0.f, 0.f, 0.f, 0.f};
#pragma unroll
        for (int i = 0; i < 16; ++i) {
          int kc = khalf * 16 + i;
          s8v a = ld16a(arow + kc * 32 + q * 8);
          s8v b = *(const s8v*)(sm.wsd + (size_t)((kc * 4 + q) * 16 + l15) * 8);
          acc = MFMA16(a, b, acc, 0, 0, 0);
        }
#pragma unroll
        for (int r = 0; r < 4; ++r) sm.gsc[wv * 512 + (q * 4 + r) * 16 + l15] = acc[r];
        __syncthreads();
        for (int oi = tid; oi < 512; oi += 256) {
          int mt2 = oi >> 8, idx = oi & 255;
          float val = sm.gsc[mt2 * 512 + idx] + sm.gsc[1024 + mt2 * 512 + idx];
          int mrow = mt2 * 16 + (idx >> 4);
          int n = (bk - 64) * 16 + (idx & 15);
          store_out(p.out, mode, ((long)mrow * 400 + (t - 1)) * 80 + n,
                    val + bf2f(p.bout[n]));
        }
      }
    } else if (bk == 69) {
      if (t > 0) {
        int b = tid >> 3, kp = tid & 7;
        const u16* hrow = hR + b * 1024 + kp * 128;
        float s = 0.f;
#pragma unroll 8
        for (int k = 0; k < 32; ++k) {                  // 128 u16 as 32x8B coherent
          union { unsigned long long u; u16 h[4]; } cu;
          cu.u = ld64a(hrow + k * 4);
#pragma unroll
          for (int j = 0; j < 4; ++j)
            s += bf2f(cu.h[j]) * bf2f(sm.wsd[kp * 128 + k * 4 + j]);
        }
        s += __shfl_xor(s, 1, 64);
        s += __shfl_xor(s, 2, 64);
        s += __shfl_xor(s, 4, 64);
        if (kp == 0)
          store_out(p.out, mode, 1024000 + (long)b * 400 + (t - 1),
                    sigm(s + bf2f(p.bstop[0])));
      }
    } else if (bk < 134) {
      stfa(&p.ctx[(bk - 70) * 256 + tid], 0.f);
    } else if (bk == 134) {
      if (tid < 32) stfa(&p.sumexp[tid], 0.f);
    }
    if (t == 400) break;
    gsync(p.bar, &sm.ep, false);

    // ---- phase A: attention for (bA, 25 positions) ----
    for (int i = tid; i < 1024; i += 256) sm.hp[i] = ldfa(&p.hp[bA * 1024 + i]);
    __syncthreads();
    {
      f4v h0a = *(const f4v*)(sm.hp + lane * 8);
      f4v h0b = *(const f4v*)(sm.hp + lane * 8 + 4);
      f4v h1a = *(const f4v*)(sm.hp + 512 + lane * 8);
      f4v h1b = *(const f4v*)(sm.hp + 512 + lane * 8 + 4);
      s8v v0 = *(const s8v*)(sm.v + lane * 8);
      s8v v1 = *(const s8v*)(sm.v + 512 + lane * 8);
      for (int si = wv; si < 25; si += 4) {
        const u16* prow = sm.proj + si * 1024;
        s8v p0 = *(const s8v*)(prow + lane * 8);
        s8v p1 = *(const s8v*)(prow + 512 + lane * 8);
        float part = 0.f;
#pragma unroll
        for (int jj = 0; jj < 4; ++jj) {
          part += tanh_(bf2f((u16)p0[jj]) + h0a[jj]) * bf2f((u16)v0[jj]);
          part += tanh_(bf2f((u16)p0[jj + 4]) + h0b[jj]) * bf2f((u16)v0[jj + 4]);
          part += tanh_(bf2f((u16)p1[jj]) + h1a[jj]) * bf2f((u16)v1[jj]);
          part += tanh_(bf2f((u16)p1[jj + 4]) + h1b[jj]) * bf2f((u16)v1[jj + 4]);
        }
#pragma unroll
        for (int off = 32; off >= 1; off >>= 1) part += __shfl_xor(part, off, 64);
        if (lane == 0) sm.exl[si] = __builtin_amdgcn_exp2f(1.44269504f * part);
      }
    }
    __syncthreads();
    if (tid == 0) {
      float ss = 0.f;
      for (int i = 0; i < 25; ++i) ss += sm.exl[i];
      atomicAdd(&p.sumexp[bA], ss);
    }
    {
      int e0 = tid * 2;
      const u16* eb = p.enc_out + (long)(bA * 200 + s0A) * 512 + e0;  // plain: immutable, L2-hot
      float a0 = 0.f, a1 = 0.f;
#pragma unroll 5
      for (int i = 0; i < 25; ++i) {
        float w = sm.exl[i];
        unsigned pr = *(const unsigned*)(eb + (size_t)i * 512);
        a0 += w * bf2f((u16)(pr & 0xffffu));
        a1 += w * bf2f((u16)(pr >> 16));
      }
      atomicAdd(&p.ctx[bA * 512 + e0], a0);
      atomicAdd(&p.ctx[bA * 512 + e0 + 1], a1);
    }
    gsync(p.bar, &sm.ep, false);

    // ---- phase G: gates GEMM (K=1632, 4-wave K-split) + LSTM cell + aligns ----
    {
      int mtile = wv & 1, khalf = wv >> 1;
      int m = mtile * 16 + l15;
      float rsm = __builtin_amdgcn_rcpf(ldfa(&p.sumexp[m]));
      const u16* melrow = p.mel + ((long)m * 400 + (t - 1)) * 80;
      const u16* hrow = hR + m * 1024;
      const float* crow = p.ctx + m * 512;
      f4v acc;
      float b0 = (khalf == 0) ? dbias : 0.f;
      acc[0] = b0; acc[1] = b0; acc[2] = b0; acc[3] = b0;
      for (int kc = khalf; kc < 51; kc += 2) {
        int k8 = kc * 32 + q * 8;
        s8v a;
        if (k8 < 80) {
          a = (t == 0) ? zero8 : *(const s8v*)(melrow + k8);
        } else if (k8 < 592) {
          const float* cr = crow + (k8 - 80);
          union { unsigned long long u[4]; float f[8]; } cu;
          cu.u[0] = ld64a(cr);     cu.u[1] = ld64a(cr + 2);
          cu.u[2] = ld64a(cr + 4); cu.u[3] = ld64a(cr + 6);
          s8v t8;
#pragma unroll
          for (int jj = 0; jj < 8; ++jj) t8[jj] = (short)f2bf(cu.f[jj] * rsm);
          a = t8;
        } else if (k8 < 1616) {
          a = ld16a(hrow + (k8 - 592));
        } else {
          a = zero8;
        }
        s8v b = *(const s8v*)(sm.W + (size_t)((kc * 4 + q) * 16 + l15) * 8);
        acc = MFMA16(a, b, acc, 0, 0, 0);
      }
#pragma unroll
      for (int r = 0; r < 4; ++r) sm.gsc[wv * 512 + (q * 4 + r) * 16 + l15] = acc[r];
    }
    __syncthreads();
    if (tid < 128) {
      int bl = tid >> 2, jj = tid & 3;
      int mt2 = bl >> 4;
      const float* g0 = sm.gsc + mt2 * 512 + (bl & 15) * 16;
      const float* g1 = g0 + 1024;
      float iG = g0[jj] + g1[jj];
      float fG = g0[4 + jj] + g1[4 + jj];
      float gG = g0[8 + jj] + g1[8 + jj];
      float oG = g0[12 + jj] + g1[12 + jj];
      float cold = sm.cst[tid];
      float cn = sigm(fG) * cold + sigm(iG) * tanh_(gG);
      float hn = sigm(oG) * tanh_(cn);
      sm.cst[tid] = cn;
      stha(&hW[(long)bl * 1024 + bk * 4 + jj], f2bf(hn));
    } else if (tid >= 192 && tid < 217) {
      int sl = tid - 192;
      float rs = __builtin_amdgcn_rcpf(ldfa(&p.sumexp[bA]));
      store_out(p.out, mode, 1036800 + ((long)bA * 400 + t) * 200 + s0A + sl,
                sm.exl[sl] * rs);
    }
    gsync(p.bar, &sm.ep, false);
  }
}

extern "C" void kernel_launch(void* const* d_in, const int* in_sizes, int n_in,
                              void* d_out, int out_size, void* d_ws, size_t ws_size,
                              hipStream_t stream) {
  char* p = (char*)d_ws;
  auto carve = [&](size_t bytes) -> char* {
    char* r = p;
    p += (bytes + 255) & ~(size_t)255;
    return r;
  };
  // --- zeroed region: h double-buffers + barrier counters ---
  char* zbase = p;
  u16* h_f = (u16*)carve(2 * 8192 * 2);
  u16* h_b = (u16*)carve(2 * 8192 * 2);
  u16* h_dec = (u16*)carve(2 * 32768 * 2);
  unsigned* bar = (unsigned*)carve(8192);
  size_t zwords = (size_t)(p - zbase) / 4;
  // --- dtype flag + canonical bf16 input copies ---
  int* flag = (int*)carve(256);
  static const int cvn[18] = {
      1024000, 37888, 262144, 262144, 1024, 262144, 262144, 1024,
      1572864, 1024, 1024, 2424832, 4194304, 4096, 81920, 80, 1024, 1 };
  u16* cv[18];
  for (int i = 0; i < 18; ++i) cv[i] = (u16*)carve((size_t)cvn[i] * 2);
  // --- runtime buffers ---
  u16* enc_out = (u16*)carve(3276800ull * 2);
  u16* proj = (u16*)carve(6553600ull * 2);
  float* hp = (float*)carve(32768 * 4);
  float* ctx = (float*)carve(16384 * 4);
  float* sumexp = (float*)carve(64 * 4);

  hipLaunchKernelGGL(k_detect, dim3(1), dim3(256), 0, stream,
                     (const u16*)d_in[2], flag);
  for (int i = 0; i < 18; ++i) {
    int n = in_sizes[i + 1];
    int blocks = (n + 255) / 256; if (blocks > 128) blocks = 128;
    hipLaunchKernelGGL(k_conv, dim3(blocks), dim3(256), 0, stream,
                       (const void*)d_in[i + 1], cv[i], n, (const int*)flag);
  }
  hipLaunchKernelGGL(k_zero, dim3(96), dim3(256), 0, stream,
                     (unsigned int*)zbase, (int)zwords);

  P prm;
  prm.text = (const int*)d_in[0];
  prm.mel = cv[0];   prm.emb = cv[1];
  prm.eWihF = cv[2]; prm.eWhhF = cv[3]; prm.ebF = cv[4];
  prm.eWihB = cv[5]; prm.eWhhB = cv[6]; prm.ebB = cv[7];
  prm.Ws = cv[8];    prm.bs = cv[9];    prm.vv = cv[10];
  prm.dWih = cv[11]; prm.dWhh = cv[12]; prm.db = cv[13];
  prm.Wout = cv[14]; prm.bout = cv[15]; prm.Wstop = cv[16]; prm.bstop = cv[17];
  prm.enc_out = enc_out; prm.proj = proj;
  prm.hp = hp; prm.ctx = ctx; prm.sumexp = sumexp;
  prm.h_f = h_f; prm.h_b = h_b; prm.h_dec = h_dec;
  prm.out = d_out; prm.flag = flag; prm.bar = bar;
  void* kargs[] = { (void*)&prm };
  (void)hipLaunchCooperativeKernel((void*)k_all, dim3(256), dim3(256), kargs, 0, stream);
}

// Round 8
// 11753.167 us; speedup vs baseline: 3.7806x; 1.0085x over previous
//
#include <hip/hip_runtime.h>

typedef unsigned short u16;
typedef short s8v __attribute__((ext_vector_type(8)));
typedef float f4v __attribute__((ext_vector_type(4)));

#define MFMA16 __builtin_amdgcn_mfma_f32_16x16x32_bf16
#define SCOPE_AGENT __HIP_MEMORY_SCOPE_AGENT

// ---------- scalar helpers ----------
__device__ __forceinline__ float bf2f(u16 u) {
  union { unsigned int i; float f; } c; c.i = ((unsigned int)u) << 16; return c.f;
}
__device__ __forceinline__ u16 f2bf(float f) {
  union { float f; unsigned int i; } c; c.f = f;
  unsigned int i = c.i;
  unsigned int r = i + 0x7FFFu + ((i >> 16) & 1u);  // RNE
  return (u16)(r >> 16);
}
__device__ __forceinline__ float sigm(float x) {
  float e = __builtin_amdgcn_exp2f(-1.44269504f * x);
  return __builtin_amdgcn_rcpf(1.0f + e);
}
__device__ __forceinline__ float tanh_(float x) {
  float e = __builtin_amdgcn_exp2f(2.88539009f * x);   // e^(2x)
  return 1.0f - 2.0f * __builtin_amdgcn_rcpf(e + 1.0f);
}
__device__ __forceinline__ void store_out(void* out, int mode, long idx, float v) {
  if (mode) ((float*)out)[idx] = v;
  else      ((u16*)out)[idx] = f2bf(v);
}

// ---------- coherent (agent-scope, fence-free) comm helpers ----------
__device__ __forceinline__ unsigned long long ld64a(const void* p) {
  return __hip_atomic_load((const unsigned long long*)p, __ATOMIC_RELAXED, SCOPE_AGENT);
}
__device__ __forceinline__ s8v ld16a(const void* p) {
  union { unsigned long long u[2]; s8v v; } c;
  c.u[0] = ld64a(p);
  c.u[1] = ld64a((const char*)p + 8);
  return c.v;
}
__device__ __forceinline__ float ldfa(const float* p) {
  return __hip_atomic_load(p, __ATOMIC_RELAXED, SCOPE_AGENT);
}
__device__ __forceinline__ void stfa(float* p, float v) {
  __hip_atomic_store(p, v, __ATOMIC_RELAXED, SCOPE_AGENT);
}
__device__ __forceinline__ void stha(u16* p, u16 v) {
  __hip_atomic_store(p, v, __ATOMIC_RELAXED, SCOPE_AGENT);
}
// bf16x4 dot with LDS weights (literal lane indices only -> registers)
__device__ __forceinline__ float dot4(unsigned long long u, const u16* w) {
  union { unsigned long long u; u16 h[4]; } c; c.u = u;
  return bf2f(c.h[0]) * bf2f(w[0]) + bf2f(c.h[1]) * bf2f(w[1]) +
         bf2f(c.h[2]) * bf2f(w[2]) + bf2f(c.h[3]) * bf2f(w[3]);
}

// ---------- dtype detector ----------
__global__ void k_detect(const u16* __restrict__ raw, int* __restrict__ flag) {
  __shared__ int cnt[256];
  int c = 0;
  for (int j = 0; j < 8; ++j) {
    int i = (threadIdx.x * 8 + j) * 2;
    int e = (raw[i] >> 7) & 0xFF;
    c += (e >= 130);
  }
  cnt[threadIdx.x] = c;
  __syncthreads();
  if (threadIdx.x == 0) {
    int s = 0;
    for (int i = 0; i < 256; ++i) s += cnt[i];
    *flag = (s > 64) ? 1 : 0;
  }
}

// ---------- normalize input to bf16 ----------
__global__ void k_conv(const void* __restrict__ src, u16* __restrict__ dst,
                       int n, const int* __restrict__ flag) {
  int mode = *flag;
  int i = blockIdx.x * blockDim.x + threadIdx.x;
  int st = gridDim.x * blockDim.x;
  if (mode) {
    const float* s = (const float*)src;
    for (; i < n; i += st) dst[i] = f2bf(s[i]);
  } else {
    const u16* s = (const u16*)src;
    for (; i < n; i += st) dst[i] = s[i];
  }
}

// ---------- zero init ----------
__global__ void k_zero(unsigned int* p, int n) {
  int i = blockIdx.x * blockDim.x + threadIdx.x;
  int st = gridDim.x * blockDim.x;
  for (; i < n; i += st) p[i] = 0u;
}

// ---------- device-wide barrier (2-level; light = fence-free) ----------
__device__ __forceinline__ void gsync(unsigned* bar, unsigned* sep, bool heavy) {
  __syncthreads();
  if (threadIdx.x == 0) {
    unsigned e = *sep;
    if (heavy) __threadfence();
    unsigned* leaf = bar + 128 + ((blockIdx.x & 15) << 6);
    if (__hip_atomic_fetch_add(leaf, 1u, __ATOMIC_RELAXED, SCOPE_AGENT) == e * 16u + 15u) {
      if (__hip_atomic_fetch_add(bar + 64, 1u, __ATOMIC_RELAXED, SCOPE_AGENT) == e * 16u + 15u)
        __hip_atomic_fetch_add(bar, 1u, __ATOMIC_RELAXED, SCOPE_AGENT);
    }
    while (__hip_atomic_load(bar, __ATOMIC_RELAXED, SCOPE_AGENT) <= e)
      __builtin_amdgcn_s_sleep(1);
    *sep = e + 1;
    if (heavy) __threadfence();
    asm volatile("" ::: "memory");
  }
  __syncthreads();
}

// ---------- persistent-kernel shared state (~151 KB) ----------
struct __align__(16) SMem {
  u16 W[26112];      // 52224B: dec gate-weight slice, fragment-major (enc overlay)
  u16 proj[25600];   // 51200B: this block's 25-row proj slice
  u16 wsd[16384];    // 32768B: Ws_dec / Wout col-tile (blocks 0-68), Wstop (69)
  u16 v[1024];       //  2048B
  float hp[1024];    //  4096B
  float exl[32];     //   128B
  float gsc[2048];   //  8192B: 4-wave K-split partial sums
  float cst[128];    //   512B: LSTM c-state
  unsigned ep;
};

struct P {
  const int* text;
  const u16 *emb, *eWihF, *eWhhF, *ebF, *eWihB, *eWhhB, *ebB;
  const u16 *Ws, *bs, *vv, *dWih, *dWhh, *db, *Wout, *bout, *Wstop, *bstop, *mel;
  u16 *enc_out, *proj;
  float *hp, *ctx, *sumexp;
  u16 *h_f, *h_b, *h_dec;
  void* out;
  const int* flag;
  unsigned* bar;
};

__global__ void __launch_bounds__(256, 1) k_all(P p) {
  __shared__ SMem sm;
  const int tid = threadIdx.x;
  const int bk = blockIdx.x;
  const int lane = tid & 63;
  const int wv = tid >> 6;
  const int q = lane >> 4, l15 = lane & 15;
  const s8v zero8 = {0, 0, 0, 0, 0, 0, 0, 0};
  if (tid == 0) sm.ep = 0;
  const int mode = *p.flag;

  // ================= encoder: block = (dir, mtile, 4-col group) =================
  const int dirE = bk >> 7;
  const int mtE = (bk >> 6) & 1;
  const int j0E = (bk & 63) * 4;
  {
    const u16* Wih = dirE ? p.eWihB : p.eWihF;
    const u16* Whh = dirE ? p.eWhhB : p.eWhhF;
    for (int i = tid; i < 1024; i += 256) {            // 64 frags x 16 rows
      int f = i >> 4, nl = i & 15;
      int row = (nl >> 2) * 256 + j0E + (nl & 3);      // gate*256 + col
      int k = f * 8;
      const u16* src = (k < 256) ? (Wih + row * 256 + k) : (Whh + row * 256 + k - 256);
      *(s8v*)(sm.W + (size_t)i * 8) = *(const s8v*)src;
    }
    if (tid < 64) sm.cst[tid] = 0.f;
  }
  float ebias;
  {
    const u16* eb = dirE ? p.ebB : p.ebF;
    ebias = bf2f(eb[(l15 >> 2) * 256 + j0E + (l15 & 3)]);
  }
  __syncthreads();
  {
    u16* hbuf = dirE ? p.h_b : p.h_f;
    for (int stp = 0; stp < 200; ++stp) {
      int tb = dirE ? (199 - stp) : stp;
      const u16* hR = hbuf + (stp & 1) * 8192;
      u16* hW = hbuf + ((stp + 1) & 1) * 8192;
      {
        int m = mtE * 16 + l15;
        const u16* xrow = p.emb + (long)p.text[m * 200 + tb] * 256;
        const u16* hrow = hR + m * 256;
        f4v acc;
        float b0 = (wv == 0) ? ebias : 0.f;
        acc[0] = b0; acc[1] = b0; acc[2] = b0; acc[3] = b0;
        // batched loads via NAMED scalars (no arrays -> no scratch)
        int k80 = wv * 128 + q * 8;
        s8v a0 = (k80 < 256)      ? *(const s8v*)(xrow + k80)      : ld16a(hrow + (k80 - 256));
        s8v a1 = (k80 + 32 < 256) ? *(const s8v*)(xrow + k80 + 32) : ld16a(hrow + (k80 + 32 - 256));
        s8v a2 = (k80 + 64 < 256) ? *(const s8v*)(xrow + k80 + 64) : ld16a(hrow + (k80 + 64 - 256));
        s8v a3 = (k80 + 96 < 256) ? *(const s8v*)(xrow + k80 + 96) : ld16a(hrow + (k80 + 96 - 256));
        const u16* wb = sm.W + (size_t)(((wv * 4) * 4 + q) * 16 + l15) * 8;
        acc = MFMA16(a0, *(const s8v*)(wb),        acc, 0, 0, 0);
        acc = MFMA16(a1, *(const s8v*)(wb + 512),  acc, 0, 0, 0);
        acc = MFMA16(a2, *(const s8v*)(wb + 1024), acc, 0, 0, 0);
        acc = MFMA16(a3, *(const s8v*)(wb + 1536), acc, 0, 0, 0);
#pragma unroll
        for (int r = 0; r < 4; ++r) sm.gsc[wv * 256 + (q * 4 + r) * 16 + l15] = acc[r];
      }
      __syncthreads();
      if (tid < 64) {
        int bl = tid >> 2, jj = tid & 3;
        float iG = 0.f, fG = 0.f, gG = 0.f, oG = 0.f;
#pragma unroll
        for (int w = 0; w < 4; ++w) {
          const float* g = sm.gsc + w * 256 + bl * 16;
          iG += g[jj]; fG += g[4 + jj]; gG += g[8 + jj]; oG += g[12 + jj];
        }
        float cold = sm.cst[tid];
        float cn = sigm(fG) * cold + sigm(iG) * tanh_(gG);
        float hn = sigm(oG) * tanh_(cn);
        sm.cst[tid] = cn;
        u16 hb16 = f2bf(hn);
        int b = mtE * 16 + bl;
        int col = j0E + jj;
        stha(&hW[b * 256 + col], hb16);
        p.enc_out[((long)b * 200 + tb) * 512 + dirE * 256 + col] = hb16;  // heavy fence below
      }
      gsync(p.bar, &sm.ep, stp == 199);
    }
  }

  // ================= proj = enc_out @ Ws_enc^T + bs =================
  {
    int w = bk * 4 + wv;
    for (int j = 0; j < 25; ++j) {
      int job = w * 25 + j;
      int mt = job >> 6, nt = job & 63;
      int m = mt * 16 + l15;
      const u16* arow = p.enc_out + (long)m * 512;
      int n = nt * 16 + l15;
      const u16* brow = p.Ws + (long)n * 1536;
      f4v acc = {0.f, 0.f, 0.f, 0.f};
#pragma unroll
      for (int kc = 0; kc < 16; ++kc) {
        s8v a = *(const s8v*)(arow + kc * 32 + q * 8);
        s8v b = *(const s8v*)(brow + kc * 32 + q * 8);
        acc = MFMA16(a, b, acc, 0, 0, 0);
      }
      float bias = bf2f(p.bs[n]);
#pragma unroll
      for (int r = 0; r < 4; ++r)
        p.proj[(long)(mt * 16 + q * 4 + r) * 1024 + n] = f2bf(acc[r] + bias);
    }
  }
  gsync(p.bar, &sm.ep, true);

  // ================= decoder staging (all LDS-local) =================
  const int bA = bk >> 3, s0A = (bk & 7) * 25;
  float dbias;
  {
    int j0 = bk * 4;
    for (int i = tid; i < 3264; i += 256) {             // 204 frags x 16 rows
      int f = i >> 4, nl = i & 15;
      long row = (long)(nl >> 2) * 1024 + j0 + (nl & 3);
      int k = f * 8;
      s8v val;
      if (k < 592)       val = *(const s8v*)(p.dWih + row * 592 + k);
      else if (k < 1616) val = *(const s8v*)(p.dWhh + row * 1024 + k - 592);
      else               val = zero8;
      *(s8v*)(sm.W + (size_t)i * 8) = val;
    }
    dbias = bf2f(p.db[(l15 >> 2) * 1024 + j0 + (l15 & 3)]);
    if (bk < 69) {
      const u16* base = (bk < 64) ? (p.Ws + 512) : p.Wout;
      long rstr = (bk < 64) ? 1536 : 1024;
      long r0 = (bk < 64) ? bk * 16 : (long)(bk - 64) * 16;
      for (int i = tid; i < 2048; i += 256) {           // 128 frags x 16 rows
        int f = i >> 4, nl = i & 15;
        *(s8v*)(sm.wsd + (size_t)i * 8) = *(const s8v*)(base + (r0 + nl) * rstr + f * 8);
      }
    } else if (bk == 69) {
      if (tid < 128) *(s8v*)(sm.wsd + tid * 8) = *(const s8v*)(p.Wstop + tid * 8);
    }
    const u16* psrc = p.proj + (long)(bA * 200 + s0A) * 1024;
    for (int i = tid * 8; i < 25600; i += 2048)
      *(s8v*)(sm.proj + i) = *(const s8v*)(psrc + i);
    if (tid < 128) *(s8v*)(sm.v + tid * 8) = *(const s8v*)(p.vv + tid * 8);
    if (tid < 128) sm.cst[tid] = 0.f;
  }
  __syncthreads();

  // ================= decoder loop: 3 light barriers/step =================
  for (int t = 0; t <= 400; ++t) {
    const u16* hR = p.h_dec + (t & 1) * 32768;
    u16* hW = p.h_dec + ((t + 1) & 1) * 32768;
    // ---- phase H: hp / mel(t-1) / stop(t-1) / zero ctx+sumexp ----
    if (bk < 64) {
      if (t < 400) {
        int mtile = wv & 1, khalf = wv >> 1;
        int m = mtile * 16 + l15;
        const u16* arow = hR + m * 1024;
        f4v acc = {0.f, 0.f, 0.f, 0.f};
#pragma unroll
        for (int g = 0; g < 4; ++g) {                   // 4 named loads per group
          const u16* ab = arow + (khalf * 16 + g * 4) * 32 + q * 8;
          s8v a0 = ld16a(ab);
          s8v a1 = ld16a(ab + 32);
          s8v a2 = ld16a(ab + 64);
          s8v a3 = ld16a(ab + 96);
          const u16* wb = sm.wsd + (size_t)(((khalf * 16 + g * 4) * 4 + q) * 16 + l15) * 8;
          acc = MFMA16(a0, *(const s8v*)(wb),        acc, 0, 0, 0);
          acc = MFMA16(a1, *(const s8v*)(wb + 512),  acc, 0, 0, 0);
          acc = MFMA16(a2, *(const s8v*)(wb + 1024), acc, 0, 0, 0);
          acc = MFMA16(a3, *(const s8v*)(wb + 1536), acc, 0, 0, 0);
        }
#pragma unroll
        for (int r = 0; r < 4; ++r) sm.gsc[wv * 512 + (q * 4 + r) * 16 + l15] = acc[r];
        __syncthreads();
        for (int oi = tid; oi < 512; oi += 256) {
          int mt2 = oi >> 8, idx = oi & 255;
          float val = sm.gsc[mt2 * 512 + idx] + sm.gsc[1024 + mt2 * 512 + idx];
          int mrow = mt2 * 16 + (idx >> 4);
          int n = bk * 16 + (idx & 15);
          stfa(&p.hp[mrow * 1024 + n], val);
        }
      }
    } else if (bk < 69) {
      if (t > 0) {
        int mtile = wv & 1, khalf = wv >> 1;
        int m = mtile * 16 + l15;
        const u16* arow = hR + m * 1024;
        f4v acc = {0.f, 0.f, 0.f, 0.f};
#pragma unroll
        for (int g = 0; g < 4; ++g) {
          const u16* ab = arow + (khalf * 16 + g * 4) * 32 + q * 8;
          s8v a0 = ld16a(ab);
          s8v a1 = ld16a(ab + 32);
          s8v a2 = ld16a(ab + 64);
          s8v a3 = ld16a(ab + 96);
          const u16* wb = sm.wsd + (size_t)(((khalf * 16 + g * 4) * 4 + q) * 16 + l15) * 8;
          acc = MFMA16(a0, *(const s8v*)(wb),        acc, 0, 0, 0);
          acc = MFMA16(a1, *(const s8v*)(wb + 512),  acc, 0, 0, 0);
          acc = MFMA16(a2, *(const s8v*)(wb + 1024), acc, 0, 0, 0);
          acc = MFMA16(a3, *(const s8v*)(wb + 1536), acc, 0, 0, 0);
        }
#pragma unroll
        for (int r = 0; r < 4; ++r) sm.gsc[wv * 512 + (q * 4 + r) * 16 + l15] = acc[r];
        __syncthreads();
        for (int oi = tid; oi < 512; oi += 256) {
          int mt2 = oi >> 8, idx = oi & 255;
          float val = sm.gsc[mt2 * 512 + idx] + sm.gsc[1024 + mt2 * 512 + idx];
          int mrow = mt2 * 16 + (idx >> 4);
          int n = (bk - 64) * 16 + (idx & 15);
          store_out(p.out, mode, ((long)mrow * 400 + (t - 1)) * 80 + n,
                    val + bf2f(p.bout[n]));
        }
      }
    } else if (bk == 69) {
      if (t > 0) {
        int b = tid >> 3, kp = tid & 7;
        const u16* hrow = hR + b * 1024 + kp * 128;
        float s = 0.f;
#pragma unroll
        for (int g = 0; g < 4; ++g) {                   // 8 named loads per group
          const u16* hb = hrow + g * 32;
          const u16* wb = sm.wsd + kp * 128 + g * 32;
          unsigned long long u0 = ld64a(hb);
          unsigned long long u1 = ld64a(hb + 4);
          unsigned long long u2 = ld64a(hb + 8);
          unsigned long long u3 = ld64a(hb + 12);
          unsigned long long u4 = ld64a(hb + 16);
          unsigned long long u5 = ld64a(hb + 20);
          unsigned long long u6 = ld64a(hb + 24);
          unsigned long long u7 = ld64a(hb + 28);
          s += dot4(u0, wb)      + dot4(u1, wb + 4)  + dot4(u2, wb + 8)  + dot4(u3, wb + 12)
             + dot4(u4, wb + 16) + dot4(u5, wb + 20) + dot4(u6, wb + 24) + dot4(u7, wb + 28);
        }
        s += __shfl_xor(s, 1, 64);
        s += __shfl_xor(s, 2, 64);
        s += __shfl_xor(s, 4, 64);
        if (kp == 0)
          store_out(p.out, mode, 1024000 + (long)b * 400 + (t - 1),
                    sigm(s + bf2f(p.bstop[0])));
      }
    } else if (bk < 134) {
      stfa(&p.ctx[(bk - 70) * 256 + tid], 0.f);
    } else if (bk == 134) {
      if (tid < 32) stfa(&p.sumexp[tid], 0.f);
    }
    if (t == 400) break;
    gsync(p.bar, &sm.ep, false);

    // ---- phase A: attention for (bA, 25 positions) ----
    {
      const float* hpb = p.hp + bA * 1024 + tid;        // 4 named loads, batched
      float v0 = ldfa(hpb);
      float v1 = ldfa(hpb + 256);
      float v2 = ldfa(hpb + 512);
      float v3 = ldfa(hpb + 768);
      sm.hp[tid] = v0; sm.hp[tid + 256] = v1; sm.hp[tid + 512] = v2; sm.hp[tid + 768] = v3;
    }
    __syncthreads();
    {
      f4v h0a = *(const f4v*)(sm.hp + lane * 8);
      f4v h0b = *(const f4v*)(sm.hp + lane * 8 + 4);
      f4v h1a = *(const f4v*)(sm.hp + 512 + lane * 8);
      f4v h1b = *(const f4v*)(sm.hp + 512 + lane * 8 + 4);
      s8v v0 = *(const s8v*)(sm.v + lane * 8);
      s8v v1 = *(const s8v*)(sm.v + 512 + lane * 8);
      for (int si = wv; si < 25; si += 4) {
        const u16* prow = sm.proj + si * 1024;
        s8v p0 = *(const s8v*)(prow + lane * 8);
        s8v p1 = *(const s8v*)(prow + 512 + lane * 8);
        float part = 0.f;
#pragma unroll
        for (int jj = 0; jj < 4; ++jj) {
          part += tanh_(bf2f((u16)p0[jj]) + h0a[jj]) * bf2f((u16)v0[jj]);
          part += tanh_(bf2f((u16)p0[jj + 4]) + h0b[jj]) * bf2f((u16)v0[jj + 4]);
          part += tanh_(bf2f((u16)p1[jj]) + h1a[jj]) * bf2f((u16)v1[jj]);
          part += tanh_(bf2f((u16)p1[jj + 4]) + h1b[jj]) * bf2f((u16)v1[jj + 4]);
        }
#pragma unroll
        for (int off = 32; off >= 1; off >>= 1) part += __shfl_xor(part, off, 64);
        if (lane == 0) sm.exl[si] = __builtin_amdgcn_exp2f(1.44269504f * part);
      }
    }
    __syncthreads();
    if (tid == 0) {
      float ss = 0.f;
      for (int i = 0; i < 25; ++i) ss += sm.exl[i];
      atomicAdd(&p.sumexp[bA], ss);
    }
    {
      int e0 = tid * 2;
      const u16* eb = p.enc_out + (long)(bA * 200 + s0A) * 512 + e0;  // plain: immutable, L2-hot
      float a0 = 0.f, a1 = 0.f;
#pragma unroll 5
      for (int i = 0; i < 25; ++i) {
        float w = sm.exl[i];
        unsigned pr = *(const unsigned*)(eb + (size_t)i * 512);
        a0 += w * bf2f((u16)(pr & 0xffffu));
        a1 += w * bf2f((u16)(pr >> 16));
      }
      atomicAdd(&p.ctx[bA * 512 + e0], a0);
      atomicAdd(&p.ctx[bA * 512 + e0 + 1], a1);
    }
    gsync(p.bar, &sm.ep, false);

    // ---- phase G: gates GEMM (K=1632, 4-wave K-split, named-scalar batching) ----
    {
      int mtile = wv & 1, khalf = wv >> 1;
      int m = mtile * 16 + l15;
      float rsm = __builtin_amdgcn_rcpf(ldfa(&p.sumexp[m]));
      const u16* melrow = p.mel + ((long)m * 400 + (t - 1)) * 80;
      const u16* hrow = hR + m * 1024;
      const float* crow = p.ctx + m * 512;
      // region-select load (identical semantics to the verified R2 loop body)
      auto gload = [&](int kc) -> s8v {
        int k8 = kc * 32 + q * 8;
        if (k8 < 80) {
          return (t == 0) ? zero8 : *(const s8v*)(melrow + k8);
        } else if (k8 < 592) {
          const float* cr = crow + (k8 - 80);
          union { unsigned long long u[4]; float f[8]; } cu;
          cu.u[0] = ld64a(cr);     cu.u[1] = ld64a(cr + 2);
          cu.u[2] = ld64a(cr + 4); cu.u[3] = ld64a(cr + 6);
          s8v t8;
#pragma unroll
          for (int jj = 0; jj < 8; ++jj) t8[jj] = (short)f2bf(cu.f[jj] * rsm);
          return t8;
        } else if (k8 < 1616) {
          return ld16a(hrow + (k8 - 592));
        }
        return zero8;
      };
      f4v acc;
      float b0 = (khalf == 0) ? dbias : 0.f;
      acc[0] = b0; acc[1] = b0; acc[2] = b0; acc[3] = b0;
      for (int kcg = khalf; kcg < 51; kcg += 8) {        // groups of 4 kc (stride 2)
        s8v a0 = gload(kcg);
        s8v a1 = (kcg + 2 < 51) ? gload(kcg + 2) : zero8;
        s8v a2 = (kcg + 4 < 51) ? gload(kcg + 4) : zero8;
        s8v a3 = (kcg + 6 < 51) ? gload(kcg + 6) : zero8;
        const u16* wb = sm.W + (size_t)((kcg * 4 + q) * 16 + l15) * 8;
        acc = MFMA16(a0, *(const s8v*)(wb), acc, 0, 0, 0);
        if (kcg + 2 < 51) acc = MFMA16(a1, *(const s8v*)(wb + 1024), acc, 0, 0, 0);
        if (kcg + 4 < 51) acc = MFMA16(a2, *(const s8v*)(wb + 2048), acc, 0, 0, 0);
        if (kcg + 6 < 51) acc = MFMA16(a3, *(const s8v*)(wb + 3072), acc, 0, 0, 0);
      }
#pragma unroll
      for (int r = 0; r < 4; ++r) sm.gsc[wv * 512 + (q * 4 + r) * 16 + l15] = acc[r];
    }
    __syncthreads();
    if (tid < 128) {
      int bl = tid >> 2, jj = tid & 3;
      int mt2 = bl >> 4;
      const float* g0 = sm.gsc + mt2 * 512 + (bl & 15) * 16;
      const float* g1 = g0 + 1024;
      float iG = g0[jj] + g1[jj];
      float fG = g0[4 + jj] + g1[4 + jj];
      float gG = g0[8 + jj] + g1[8 + jj];
      float oG = g0[12 + jj] + g1[12 + jj];
      float cold = sm.cst[tid];
      float cn = sigm(fG) * cold + sigm(iG) * tanh_(gG);
      float hn = sigm(oG) * tanh_(cn);
      sm.cst[tid] = cn;
      stha(&hW[(long)bl * 1024 + bk * 4 + jj], f2bf(hn));
    } else if (tid >= 192 && tid < 217) {
      int sl = tid - 192;
      float rs = __builtin_amdgcn_rcpf(ldfa(&p.sumexp[bA]));
      store_out(p.out, mode, 1036800 + ((long)bA * 400 + t) * 200 + s0A + sl,
                sm.exl[sl] * rs);
    }
    gsync(p.bar, &sm.ep, false);
  }
}

extern "C" void kernel_launch(void* const* d_in, const int* in_sizes, int n_in,
                              void* d_out, int out_size, void* d_ws, size_t ws_size,
                              hipStream_t stream) {
  char* p = (char*)d_ws;
  auto carve = [&](size_t bytes) -> char* {
    char* r = p;
    p += (bytes + 255) & ~(size_t)255;
    return r;
  };
  // --- zeroed region: h double-buffers + barrier counters ---
  char* zbase = p;
  u16* h_f = (u16*)carve(2 * 8192 * 2);
  u16* h_b = (u16*)carve(2 * 8192 * 2);
  u16* h_dec = (u16*)carve(2 * 32768 * 2);
  unsigned* bar = (unsigned*)carve(8192);
  size_t zwords = (size_t)(p - zbase) / 4;
  // --- dtype flag + canonical bf16 input copies ---
  int* flag = (int*)carve(256);
  static const int cvn[18] = {
      1024000, 37888, 262144, 262144, 1024, 262144, 262144, 1024,
      1572864, 1024, 1024, 2424832, 4194304, 4096, 81920, 80, 1024, 1 };
  u16* cv[18];
  for (int i = 0; i < 18; ++i) cv[i] = (u16*)carve((size_t)cvn[i] * 2);
  // --- runtime buffers ---
  u16* enc_out = (u16*)carve(3276800ull * 2);
  u16* proj = (u16*)carve(6553600ull * 2);
  float* hp = (float*)carve(32768 * 4);
  float* ctx = (float*)carve(16384 * 4);
  float* sumexp = (float*)carve(64 * 4);

  hipLaunchKernelGGL(k_detect, dim3(1), dim3(256), 0, stream,
                     (const u16*)d_in[2], flag);
  for (int i = 0; i < 18; ++i) {
    int n = in_sizes[i + 1];
    int blocks = (n + 255) / 256; if (blocks > 128) blocks = 128;
    hipLaunchKernelGGL(k_conv, dim3(blocks), dim3(256), 0, stream,
                       (const void*)d_in[i + 1], cv[i], n, (const int*)flag);
  }
  hipLaunchKernelGGL(k_zero, dim3(96), dim3(256), 0, stream,
                     (unsigned int*)zbase, (int)zwords);

  P prm;
  prm.text = (const int*)d_in[0];
  prm.mel = cv[0];   prm.emb = cv[1];
  prm.eWihF = cv[2]; prm.eWhhF = cv[3]; prm.ebF = cv[4];
  prm.eWihB = cv[5]; prm.eWhhB = cv[6]; prm.ebB = cv[7];
  prm.Ws = cv[8];    prm.bs = cv[9];    prm.vv = cv[10];
  prm.dWih = cv[11]; prm.dWhh = cv[12]; prm.db = cv[13];
  prm.Wout = cv[14]; prm.bout = cv[15]; prm.Wstop = cv[16]; prm.bstop = cv[17];
  prm.enc_out = enc_out; prm.proj = proj;
  prm.hp = hp; prm.ctx = ctx; prm.sumexp = sumexp;
  prm.h_f = h_f; prm.h_b = h_b; prm.h_dec = h_dec;
  prm.out = d_out; prm.flag = flag; prm.bar = bar;
  void* kargs[] = { (void*)&prm };
  (void)hipLaunchCooperativeKernel((void*)k_all, dim3(256), dim3(256), kargs, 0, stream);
}